// Round 2
// baseline (3686.407 us; speedup 1.0000x reference)
//
#include <hip/hip_runtime.h>
#include <math.h>

#define N_NODES 10000
#define N_EDGES 40000

// ---------------------------------------------------------------------------
// Tensor-product path tables (compile-time, derived from the reference irreps)
// kind: 0=(l1,l2,l3)=(0,0,0)  1=(0,1,1)  2=(1,0,1)  3=(1,1,0)  4=(1,1,1)
// coef = sqrt(2*l3+1)/sqrt(fan[i3]) * CG scalar factor (1, 1/sqrt3, or 1/sqrt6)
// ---------------------------------------------------------------------------
struct PathT { int woff, m1, l2m3, inoff, outoff, kind; float coef; };

__device__ const PathT PATHS0[2] = {
  {   0,32,5, 0, 0,0, 0.17677670f},
  {1024,32,3, 0,32,1, 0.17677670f},
};
__device__ const PathT PATHS1[5] = {
  {   0,32,5, 0, 0,0, 0.15811388f},
  {1024,32,3, 0,32,1, 0.15811388f},
  {1280, 8,3,32,32,2, 0.15811388f},
  {1344, 8,5,32, 0,3, 0.09128709f},
  {1600, 8,3,32,56,4, 0.25f},
};
__device__ const PathT PATHS2[8] = {
  {   0,32,5, 0, 0,0, 0.15811388f},
  {1024,32,3, 0,32,1, 0.14433757f},
  {1280, 8,3,32,32,2, 0.14433757f},
  {1344, 8,5,32, 0,3, 0.09128709f},
  {1600, 8,3,32,56,4, 0.17677670f},
  {1664, 8,3,56,56,2, 0.25f},
  {1728, 8,3,56,32,4, 0.10206207f},
  {1792, 8,5,56,80,3, 0.20412415f},
};
// L3: fan[0]=40, fan[1]=48, fan[2]=48, fan[3]=40
__device__ const PathT PATHS3[10] = {
  {   0,32,5, 0, 0,0, 0.15811388f},   // (0,0,0)->i3=0  1/sqrt(40)
  {1024,32,3, 0,32,1, 0.14433757f},   // (0,1,1)->i3=1  1/sqrt(48)
  {1280, 8,3,32,32,2, 0.14433757f},   // (1,0,1)->i3=1  1/sqrt(48)
  {1344, 8,5,32, 0,3, 0.09128709f},   // (1,1,0)->i3=0  1/sqrt(40*3)
  {1600, 8,3,32,56,4, 0.10206207f},   // (1,1,2)->i3=2  sqrt(3)/sqrt(48*6) [FIXED]
  {1664, 8,3,56,56,2, 0.14433757f},   // (2,0,2)->i3=2  1/sqrt(48)         [FIXED]
  {1728, 8,3,56,32,4, 0.10206207f},   // (2,1,1)->i3=1  sqrt(3)/sqrt(48*6)
  {1792, 8,5,56,80,3, 0.09128709f},   // (2,1,3)->i3=3  1/sqrt(40*3)
  {2048,32,5,80,80,0, 0.15811388f},   // (3,0,3)->i3=3  1/sqrt(40)
  {3072,32,3,80,56,1, 0.14433757f},   // (3,1,2)->i3=2  1/sqrt(48)         [FIXED]
};

// ---------------------------------------------------------------------------
// K0: timestep embedding per node
// ---------------------------------------------------------------------------
__global__ void ksemb(const float* __restrict__ sigma, float* __restrict__ semb)
{
    int n = blockIdx.x * 256 + threadIdx.x;
    if (n >= N_NODES) return;
    // t = ln(sigma/SIGMA_MIN)/ln(100) * 10000
    float t = logf(sigma[n] * (1.0f / 0.031415926535897934f)) * 2171.4724095f;
#pragma unroll
    for (int j = 0; j < 16; ++j) {
        float f = expf(-0.61402269f * (float)j);
        float a = t * f;
        semb[n * 32 + j]      = sinf(a);
        semb[n * 32 + 16 + j] = cosf(a);
    }
}

// ---------------------------------------------------------------------------
// K1: node MLP: na[:, :32] = relu([x, semb] @ w1 + b1) @ w2 + b2
// block = 256 threads = 8 nodes x 32 channels
// ---------------------------------------------------------------------------
__global__ void knodemlp(const float* __restrict__ x, const float* __restrict__ semb,
                         const float* __restrict__ w1, const float* __restrict__ b1,
                         const float* __restrict__ w2, const float* __restrict__ b2,
                         float* __restrict__ na)
{
    __shared__ float xin[8][106];
    __shared__ float h1[8][32];
    int tid = threadIdx.x;
    int n0  = blockIdx.x * 8;
    for (int idx = tid; idx < 8 * 106; idx += 256) {
        int e = idx / 106, q = idx % 106;
        int n = n0 + e;
        float v = 0.f;
        if (n < N_NODES) v = (q < 74) ? x[n * 74 + q] : semb[n * 32 + (q - 74)];
        xin[e][q] = v;
    }
    __syncthreads();
    {
        int e = tid / 32, c = tid % 32;
        float s = b1[c];
        for (int f = 0; f < 106; ++f) s += xin[e][f] * w1[f * 32 + c];
        h1[e][c] = fmaxf(s, 0.f);
    }
    __syncthreads();
    {
        int e = tid / 32, c = tid % 32;
        int n = n0 + e;
        if (n < N_NODES) {
            float s = b2[c];
#pragma unroll
            for (int f = 0; f < 32; ++f) s += h1[e][f] * w2[f * 32 + c];
            na[n * 112 + c] = s;
        }
    }
}

// ---------------------------------------------------------------------------
// K2: per-edge precompute: sh(4), gaussian smearing, edge MLP -> eemb(32),
//     in-degree count. block = 256 threads = 8 edges x 32 channels
// ---------------------------------------------------------------------------
__global__ void kedgepre(const float* __restrict__ pos, const float* __restrict__ eattr_in,
                         const float* __restrict__ semb, const int* __restrict__ ei,
                         const float* __restrict__ w1, const float* __restrict__ b1,
                         const float* __restrict__ w2, const float* __restrict__ b2,
                         float* __restrict__ sh, float* __restrict__ eemb, int* __restrict__ cnt)
{
    __shared__ float ea[8][86];
    __shared__ float h1[8][32];
    __shared__ float dl[8];
    __shared__ int   sl[8];
    int tid = threadIdx.x;
    int e0  = blockIdx.x * 8;
    if (tid < 8) {
        int ge = e0 + tid;
        int s = ei[ge], d = ei[N_EDGES + ge];
        sl[tid] = s;
        float dx = pos[d * 3 + 0] - pos[s * 3 + 0];
        float dy = pos[d * 3 + 1] - pos[s * 3 + 1];
        float dz = pos[d * 3 + 2] - pos[s * 3 + 2];
        float dist = sqrtf(dx * dx + dy * dy + dz * dz);
        dist = fmaxf(dist, 1e-6f);
        dl[tid] = dist;
        float inv = 1.7320508f / dist;
        sh[ge * 4 + 0] = 1.f;
        sh[ge * 4 + 1] = dx * inv;
        sh[ge * 4 + 2] = dy * inv;
        sh[ge * 4 + 3] = dz * inv;
        atomicAdd(&cnt[d], 1);
    }
    __syncthreads();
    for (int idx = tid; idx < 8 * 86; idx += 256) {
        int e = idx / 86, q = idx % 86;
        int ge = e0 + e;
        float v;
        if (q < 4)       v = eattr_in[ge * 4 + q];
        else if (q < 36) v = semb[sl[e] * 32 + (q - 4)];
        else {
            int qq = q - 36;
            float off = 5.f * (float)qq / 49.f;
            float dd  = dl[e] - off;
            v = expf(-48.02f * dd * dd);
        }
        ea[e][q] = v;
    }
    __syncthreads();
    {
        int e = tid / 32, c = tid % 32;
        float s = b1[c];
        for (int f = 0; f < 86; ++f) s += ea[e][f] * w1[f * 32 + c];
        h1[e][c] = fmaxf(s, 0.f);
    }
    __syncthreads();
    {
        int e = tid / 32, c = tid % 32;
        float s = b2[c];
#pragma unroll
        for (int f = 0; f < 32; ++f) s += h1[e][f] * w2[f * 32 + c];
        eemb[(e0 + e) * 32 + c] = s;
    }
}

// ---------------------------------------------------------------------------
// K3: fused per-edge fc1 -> fc2 -> tensor product -> atomic scatter.
// block = 256 threads handles 8 edges. Each thread owns fc2 columns
// j = tid + 256*kk and accumulates w for all 8 edges in registers (8 FMA per
// weight load). TP epilogue decodes j -> (path, u, w3) and accumulates into
// LDS out tile, then scatters with f32 global atomics.
// ---------------------------------------------------------------------------
template <int L>
__global__ __launch_bounds__(256, 2) void ktp(
    const float* __restrict__ na, const float* __restrict__ eemb,
    const float* __restrict__ sh, const int* __restrict__ ei,
    const float* __restrict__ fc1w, const float* __restrict__ fc1b,
    const float* __restrict__ fc2w, const float* __restrict__ fc2b,
    float* __restrict__ out_tp)
{
    constexpr int NCOL = (L == 0 ? 1280 : L == 1 ? 1664 : L == 2 ? 2048 : 3328);
    constexpr int DIN  = (L == 0 ? 32 : L == 1 ? 56 : L == 2 ? 80 : 112);
    constexpr int DOUT = (L == 0 ? 56 : L == 1 ? 80 : 112);
    constexpr int NP   = (L == 0 ? 2 : L == 1 ? 5 : L == 2 ? 8 : 10);
    constexpr int MAXC = (NCOL + 255) / 256;
    const PathT* PT = (L == 0 ? PATHS0 : L == 1 ? PATHS1 : L == 2 ? PATHS2 : PATHS3);

    __shared__ float eac[8][96];
    __shared__ float hbuf[8][96];
    __shared__ float xs[8][112];
    __shared__ float shl[8][4];
    __shared__ float oacc[8][112];
    __shared__ int   sdn[8], ddn[8];

    int tid = threadIdx.x;
    int e0  = blockIdx.x * 8;
    if (tid < 8) { sdn[tid] = ei[e0 + tid]; ddn[tid] = ei[N_EDGES + e0 + tid]; }
    __syncthreads();

    for (int idx = tid; idx < 8 * 96; idx += 256) {
        int e = idx / 96, c = idx % 96;
        float v;
        if (c < 32)      v = eemb[(e0 + e) * 32 + c];
        else if (c < 64) v = na[sdn[e] * 112 + (c - 32)];
        else             v = na[ddn[e] * 112 + (c - 64)];
        eac[e][c] = v;
    }
    for (int idx = tid; idx < 8 * DIN; idx += 256) {
        int e = idx / DIN, d = idx % DIN;
        xs[e][d] = na[sdn[e] * 112 + d];
    }
    if (tid < 32) { int e = tid >> 2, q = tid & 3; shl[e][q] = sh[(e0 + e) * 4 + q]; }
    for (int idx = tid; idx < 8 * 112; idx += 256) { oacc[idx / 112][idx % 112] = 0.f; }
    __syncthreads();

    // h = relu(eac @ fc1_w + fc1_b)  (768 outputs over 256 threads)
    for (int oi = tid; oi < 8 * 96; oi += 256) {
        int e = oi / 96, c = oi % 96;
        float s = fc1b[c];
#pragma unroll 8
        for (int f = 0; f < 96; ++f) s += eac[e][f] * fc1w[f * 96 + c];
        hbuf[e][c] = fmaxf(s, 0.f);
    }
    __syncthreads();

    // fc2: acc[kk][e] = fc2_b[j] + sum_c h[e][c]*W2[c][j]
    float acc[MAXC][8];
#pragma unroll
    for (int kk = 0; kk < MAXC; ++kk) {
        int j = tid + 256 * kk;
        float b = (j < NCOL) ? fc2b[j] : 0.f;
#pragma unroll
        for (int e = 0; e < 8; ++e) acc[kk][e] = b;
    }
    for (int c = 0; c < 96; ++c) {
        float h8[8];
#pragma unroll
        for (int e = 0; e < 8; ++e) h8[e] = hbuf[e][c];
        const float* wrow = fc2w + c * NCOL;
#pragma unroll
        for (int kk = 0; kk < MAXC; ++kk) {
            int j = tid + 256 * kk;
            if (j < NCOL) {
                float wv = wrow[j];
#pragma unroll
                for (int e = 0; e < 8; ++e) acc[kk][e] += h8[e] * wv;
            }
        }
    }

    // tensor-product epilogue
#pragma unroll
    for (int kk = 0; kk < MAXC; ++kk) {
        int j = tid + 256 * kk;
        if (j >= NCOL) continue;
        int p = 0;
#pragma unroll
        for (int q = 1; q < NP; ++q) if (j >= PT[q].woff) p = q;
        PathT P  = PT[p];
        int rel  = j - P.woff;
        int u    = rel >> P.l2m3;
        int w3   = rel & ((1 << P.l2m3) - 1);
        if (P.kind == 0) {
#pragma unroll
            for (int e = 0; e < 8; ++e)
                atomicAdd(&oacc[e][P.outoff + w3], P.coef * xs[e][P.inoff + u] * acc[kk][e]);
        } else if (P.kind == 1) {
#pragma unroll
            for (int e = 0; e < 8; ++e) {
                float t = P.coef * xs[e][P.inoff + u] * acc[kk][e];
                atomicAdd(&oacc[e][P.outoff + 3 * w3 + 0], t * shl[e][1]);
                atomicAdd(&oacc[e][P.outoff + 3 * w3 + 1], t * shl[e][2]);
                atomicAdd(&oacc[e][P.outoff + 3 * w3 + 2], t * shl[e][3]);
            }
        } else if (P.kind == 2) {
#pragma unroll
            for (int e = 0; e < 8; ++e) {
                float t = P.coef * acc[kk][e];
                atomicAdd(&oacc[e][P.outoff + 3 * w3 + 0], t * xs[e][P.inoff + 3 * u + 0]);
                atomicAdd(&oacc[e][P.outoff + 3 * w3 + 1], t * xs[e][P.inoff + 3 * u + 1]);
                atomicAdd(&oacc[e][P.outoff + 3 * w3 + 2], t * xs[e][P.inoff + 3 * u + 2]);
            }
        } else if (P.kind == 3) {
#pragma unroll
            for (int e = 0; e < 8; ++e) {
                float s = xs[e][P.inoff + 3 * u + 0] * shl[e][1]
                        + xs[e][P.inoff + 3 * u + 1] * shl[e][2]
                        + xs[e][P.inoff + 3 * u + 2] * shl[e][3];
                atomicAdd(&oacc[e][P.outoff + w3], P.coef * s * acc[kk][e]);
            }
        } else {
#pragma unroll
            for (int e = 0; e < 8; ++e) {
                float x0 = xs[e][P.inoff + 3 * u + 0];
                float x1 = xs[e][P.inoff + 3 * u + 1];
                float x2 = xs[e][P.inoff + 3 * u + 2];
                float y0 = shl[e][1], y1 = shl[e][2], y2 = shl[e][3];
                float t  = P.coef * acc[kk][e];
                atomicAdd(&oacc[e][P.outoff + 3 * w3 + 0], t * (x1 * y2 - x2 * y1));
                atomicAdd(&oacc[e][P.outoff + 3 * w3 + 1], t * (x2 * y0 - x0 * y2));
                atomicAdd(&oacc[e][P.outoff + 3 * w3 + 2], t * (x0 * y1 - x1 * y0));
            }
        }
    }
    __syncthreads();

    // scatter to out_tp[dst]
    for (int idx = tid; idx < 8 * DOUT; idx += 256) {
        int e = idx / DOUT, d = idx % DOUT;
        unsafeAtomicAdd(&out_tp[ddn[e] * 112 + d], oacc[e][d]);
    }
}

// ---------------------------------------------------------------------------
// K4: out = out_tp / max(cnt,1) + pad(node_attr)
// ---------------------------------------------------------------------------
__global__ void knodeout(const float* __restrict__ tp, const int* __restrict__ cnt,
                         const float* __restrict__ na, float* __restrict__ outb,
                         int din, int dout)
{
    int idx = blockIdx.x * 256 + threadIdx.x;
    if (idx >= N_NODES * dout) return;
    int n = idx / dout, d = idx % dout;
    float c = fmaxf((float)cnt[n], 1.f);
    float v = tp[n * 112 + d] / c + (d < din ? na[n * 112 + d] : 0.f);
    outb[n * 112 + d] = v;
}

// ---------------------------------------------------------------------------
// K5: per-dim sums (one block per output dim)
// ---------------------------------------------------------------------------
__global__ void kstats(const float* __restrict__ outb, float* __restrict__ sums,
                       float* __restrict__ sumsq)
{
    int d = blockIdx.x;
    int tid = threadIdx.x;
    float s = 0.f, s2 = 0.f;
    for (int n = tid; n < N_NODES; n += 256) {
        float v = outb[n * 112 + d];
        s += v; s2 += v * v;
    }
    __shared__ float r1[256], r2[256];
    r1[tid] = s; r2[tid] = s2;
    __syncthreads();
    for (int o = 128; o > 0; o >>= 1) {
        if (tid < o) { r1[tid] += r1[tid + o]; r2[tid] += r2[tid + o]; }
        __syncthreads();
    }
    if (tid == 0) { sums[d] = r1[0]; sumsq[d] = r2[0]; }
}

// ---------------------------------------------------------------------------
// K6: finalize batchnorm scale/bias per dim
// scalar dims: d<32 or d>=vend. vector dims: [32, vend), channel = 3 dims.
// ---------------------------------------------------------------------------
__global__ void kfin(const float* __restrict__ sums, const float* __restrict__ sumsq,
                     float* __restrict__ scale, float* __restrict__ bias,
                     int dout, int vend)
{
    int d = threadIdx.x;
    if (d >= dout) return;
    const float invN = 1.f / (float)N_NODES;
    if (d < 32 || d >= vend) {
        float m   = sums[d] * invN;
        float var = sumsq[d] * invN - m * m;
        scale[d] = rsqrtf(var + 1e-5f);
        bias[d]  = m;
    } else {
        int b = 32 + ((d - 32) / 3) * 3;
        float n2 = (sumsq[b] + sumsq[b + 1] + sumsq[b + 2]) * (invN / 3.f);
        scale[d] = rsqrtf(n2 + 1e-5f);
        bias[d]  = 0.f;
    }
}

// ---------------------------------------------------------------------------
// K7: apply normalization
// ---------------------------------------------------------------------------
__global__ void kapply(const float* __restrict__ outb, const float* __restrict__ scale,
                       const float* __restrict__ bias, float* __restrict__ dst, int dout)
{
    int idx = blockIdx.x * 256 + threadIdx.x;
    if (idx >= N_NODES * dout) return;
    int n = idx / dout, d = idx % dout;
    dst[n * 112 + d] = (outb[n * 112 + d] - bias[d]) * scale[d];
}

// ---------------------------------------------------------------------------
extern "C" void kernel_launch(void* const* d_in, const int* in_sizes, int n_in,
                              void* d_out, int out_size, void* d_ws, size_t ws_size,
                              hipStream_t stream)
{
    (void)in_sizes; (void)n_in; (void)out_size; (void)ws_size;
    const float* x     = (const float*)d_in[0];
    const float* pos   = (const float*)d_in[1];
    const float* sigma = (const float*)d_in[2];
    const float* eain  = (const float*)d_in[3];
    const float* nw1 = (const float*)d_in[4];  const float* nb1 = (const float*)d_in[5];
    const float* nw2 = (const float*)d_in[6];  const float* nb2 = (const float*)d_in[7];
    const float* ew1 = (const float*)d_in[8];  const float* eb1 = (const float*)d_in[9];
    const float* ew2 = (const float*)d_in[10]; const float* eb2 = (const float*)d_in[11];
    const float* fc1w = (const float*)d_in[12];
    const float* fc1b = (const float*)d_in[13];
    const float* fc2w[4] = {(const float*)d_in[14], (const float*)d_in[16],
                            (const float*)d_in[18], (const float*)d_in[20]};
    const float* fc2b[4] = {(const float*)d_in[15], (const float*)d_in[17],
                            (const float*)d_in[19], (const float*)d_in[21]};
    const int* ei = (const int*)d_in[22];

    float* ws   = (float*)d_ws;
    float* semb = ws + 0;            // N*32
    float* na   = ws + 320000;       // N*112
    float* outb = ws + 1440000;      // N*112
    float* tp   = ws + 2560000;      // N*112
    float* sh   = ws + 3680000;      // E*4
    float* eemb = ws + 3840000;      // E*32
    int*   cnt  = (int*)(ws + 5120000); // N
    float* sums  = ws + 5130000;     // 112
    float* sumsq = ws + 5130112;     // 112
    float* scale = ws + 5130224;     // 112
    float* bias  = ws + 5130336;     // 112
    float* out = (float*)d_out;

    hipMemsetAsync(cnt, 0, N_NODES * sizeof(int), stream);
    ksemb<<<(N_NODES + 255) / 256, 256, 0, stream>>>(sigma, semb);
    knodemlp<<<N_NODES / 8, 256, 0, stream>>>(x, semb, nw1, nb1, nw2, nb2, na);
    kedgepre<<<N_EDGES / 8, 256, 0, stream>>>(pos, eain, semb, ei, ew1, eb1, ew2, eb2,
                                              sh, eemb, cnt);

    const int DIN_[4]  = {32, 56, 80, 112};
    const int DOUT_[4] = {56, 80, 112, 112};
    const int VEND_[4] = {56, 80, 80, 80};
    for (int L = 0; L < 4; ++L) {
        hipMemsetAsync(tp, 0, (size_t)N_NODES * 112 * sizeof(float), stream);
        switch (L) {
        case 0: ktp<0><<<N_EDGES / 8, 256, 0, stream>>>(na, eemb, sh, ei, fc1w + 0 * 9216,
                    fc1b + 0 * 96, fc2w[0], fc2b[0], tp); break;
        case 1: ktp<1><<<N_EDGES / 8, 256, 0, stream>>>(na, eemb, sh, ei, fc1w + 1 * 9216,
                    fc1b + 1 * 96, fc2w[1], fc2b[1], tp); break;
        case 2: ktp<2><<<N_EDGES / 8, 256, 0, stream>>>(na, eemb, sh, ei, fc1w + 2 * 9216,
                    fc1b + 2 * 96, fc2w[2], fc2b[2], tp); break;
        default: ktp<3><<<N_EDGES / 8, 256, 0, stream>>>(na, eemb, sh, ei, fc1w + 3 * 9216,
                    fc1b + 3 * 96, fc2w[3], fc2b[3], tp); break;
        }
        knodeout<<<(N_NODES * DOUT_[L] + 255) / 256, 256, 0, stream>>>(tp, cnt, na, outb,
                                                                       DIN_[L], DOUT_[L]);
        kstats<<<DOUT_[L], 256, 0, stream>>>(outb, sums, sumsq);
        kfin<<<1, 128, 0, stream>>>(sums, sumsq, scale, bias, DOUT_[L], VEND_[L]);
        float* dstp = (L == 3) ? out : na;
        kapply<<<(N_NODES * DOUT_[L] + 255) / 256, 256, 0, stream>>>(outb, scale, bias,
                                                                     dstp, DOUT_[L]);
    }
}

// Round 3
// 3245.932 us; speedup vs baseline: 1.1357x; 1.1357x over previous
//
#include <hip/hip_runtime.h>
#include <math.h>

#define N_NODES 10000
#define N_EDGES 40000

// ---------------------------------------------------------------------------
// Tensor-product path tables (compile-time, derived from the reference irreps)
// kind: 0=(l1,l2,l3)=(0,0,0)  1=(0,1,1)  2=(1,0,1)  3=(1,1,0)  4=(1,1,1)
// coef = sqrt(2*l3+1)/sqrt(fan[i3]) * CG scalar factor (1, 1/sqrt3, or 1/sqrt6)
// ---------------------------------------------------------------------------
struct PathT { int woff, m1, l2m3, inoff, outoff, kind; float coef; };

__device__ const PathT PATHS0[2] = {
  {   0,32,5, 0, 0,0, 0.17677670f},
  {1024,32,3, 0,32,1, 0.17677670f},
};
__device__ const PathT PATHS1[5] = {
  {   0,32,5, 0, 0,0, 0.15811388f},
  {1024,32,3, 0,32,1, 0.15811388f},
  {1280, 8,3,32,32,2, 0.15811388f},
  {1344, 8,5,32, 0,3, 0.09128709f},
  {1600, 8,3,32,56,4, 0.25f},
};
__device__ const PathT PATHS2[8] = {
  {   0,32,5, 0, 0,0, 0.15811388f},
  {1024,32,3, 0,32,1, 0.14433757f},
  {1280, 8,3,32,32,2, 0.14433757f},
  {1344, 8,5,32, 0,3, 0.09128709f},
  {1600, 8,3,32,56,4, 0.17677670f},
  {1664, 8,3,56,56,2, 0.25f},
  {1728, 8,3,56,32,4, 0.10206207f},
  {1792, 8,5,56,80,3, 0.20412415f},
};
// L3: fan[0]=40, fan[1]=48, fan[2]=48, fan[3]=40
__device__ const PathT PATHS3[10] = {
  {   0,32,5, 0, 0,0, 0.15811388f},
  {1024,32,3, 0,32,1, 0.14433757f},
  {1280, 8,3,32,32,2, 0.14433757f},
  {1344, 8,5,32, 0,3, 0.09128709f},
  {1600, 8,3,32,56,4, 0.10206207f},
  {1664, 8,3,56,56,2, 0.14433757f},
  {1728, 8,3,56,32,4, 0.10206207f},
  {1792, 8,5,56,80,3, 0.09128709f},
  {2048,32,5,80,80,0, 0.15811388f},
  {3072,32,3,80,56,1, 0.14433757f},
};

// ---------------------------------------------------------------------------
// K0: timestep embedding per node
// ---------------------------------------------------------------------------
__global__ void ksemb(const float* __restrict__ sigma, float* __restrict__ semb)
{
    int n = blockIdx.x * 256 + threadIdx.x;
    if (n >= N_NODES) return;
    float t = logf(sigma[n] * (1.0f / 0.031415926535897934f)) * 2171.4724095f;
#pragma unroll
    for (int j = 0; j < 16; ++j) {
        float f = expf(-0.61402269f * (float)j);
        float a = t * f;
        semb[n * 32 + j]      = sinf(a);
        semb[n * 32 + 16 + j] = cosf(a);
    }
}

// ---------------------------------------------------------------------------
// K1: node MLP
// ---------------------------------------------------------------------------
__global__ void knodemlp(const float* __restrict__ x, const float* __restrict__ semb,
                         const float* __restrict__ w1, const float* __restrict__ b1,
                         const float* __restrict__ w2, const float* __restrict__ b2,
                         float* __restrict__ na)
{
    __shared__ float xin[8][106];
    __shared__ float h1[8][32];
    int tid = threadIdx.x;
    int n0  = blockIdx.x * 8;
    for (int idx = tid; idx < 8 * 106; idx += 256) {
        int e = idx / 106, q = idx % 106;
        int n = n0 + e;
        float v = 0.f;
        if (n < N_NODES) v = (q < 74) ? x[n * 74 + q] : semb[n * 32 + (q - 74)];
        xin[e][q] = v;
    }
    __syncthreads();
    {
        int e = tid / 32, c = tid % 32;
        float s = b1[c];
        for (int f = 0; f < 106; ++f) s += xin[e][f] * w1[f * 32 + c];
        h1[e][c] = fmaxf(s, 0.f);
    }
    __syncthreads();
    {
        int e = tid / 32, c = tid % 32;
        int n = n0 + e;
        if (n < N_NODES) {
            float s = b2[c];
#pragma unroll
            for (int f = 0; f < 32; ++f) s += h1[e][f] * w2[f * 32 + c];
            na[n * 112 + c] = s;
        }
    }
}

// ---------------------------------------------------------------------------
// K2: per-edge precompute
// ---------------------------------------------------------------------------
__global__ void kedgepre(const float* __restrict__ pos, const float* __restrict__ eattr_in,
                         const float* __restrict__ semb, const int* __restrict__ ei,
                         const float* __restrict__ w1, const float* __restrict__ b1,
                         const float* __restrict__ w2, const float* __restrict__ b2,
                         float* __restrict__ sh, float* __restrict__ eemb, int* __restrict__ cnt)
{
    __shared__ float ea[8][86];
    __shared__ float h1[8][32];
    __shared__ float dl[8];
    __shared__ int   sl[8];
    int tid = threadIdx.x;
    int e0  = blockIdx.x * 8;
    if (tid < 8) {
        int ge = e0 + tid;
        int s = ei[ge], d = ei[N_EDGES + ge];
        sl[tid] = s;
        float dx = pos[d * 3 + 0] - pos[s * 3 + 0];
        float dy = pos[d * 3 + 1] - pos[s * 3 + 1];
        float dz = pos[d * 3 + 2] - pos[s * 3 + 2];
        float dist = sqrtf(dx * dx + dy * dy + dz * dz);
        dist = fmaxf(dist, 1e-6f);
        dl[tid] = dist;
        float inv = 1.7320508f / dist;
        sh[ge * 4 + 0] = 1.f;
        sh[ge * 4 + 1] = dx * inv;
        sh[ge * 4 + 2] = dy * inv;
        sh[ge * 4 + 3] = dz * inv;
        atomicAdd(&cnt[d], 1);
    }
    __syncthreads();
    for (int idx = tid; idx < 8 * 86; idx += 256) {
        int e = idx / 86, q = idx % 86;
        int ge = e0 + e;
        float v;
        if (q < 4)       v = eattr_in[ge * 4 + q];
        else if (q < 36) v = semb[sl[e] * 32 + (q - 4)];
        else {
            int qq = q - 36;
            float off = 5.f * (float)qq / 49.f;
            float dd  = dl[e] - off;
            v = expf(-48.02f * dd * dd);
        }
        ea[e][q] = v;
    }
    __syncthreads();
    {
        int e = tid / 32, c = tid % 32;
        float s = b1[c];
        for (int f = 0; f < 86; ++f) s += ea[e][f] * w1[f * 32 + c];
        h1[e][c] = fmaxf(s, 0.f);
    }
    __syncthreads();
    {
        int e = tid / 32, c = tid % 32;
        float s = b2[c];
#pragma unroll
        for (int f = 0; f < 32; ++f) s += h1[e][f] * w2[f * 32 + c];
        eemb[(e0 + e) * 32 + c] = s;
    }
}

// ---------------------------------------------------------------------------
// K3: fused per-edge fc1 -> fc2 -> tensor product -> atomic scatter.
// fc2 processed in chunks of 1024 columns: each thread owns 4 CONSECUTIVE
// columns (float4 weight loads), accumulator acc[4][8] = 32 regs (no spill),
// TP epilogue runs per-chunk so registers retire.
// ---------------------------------------------------------------------------
template <int L>
__global__ __launch_bounds__(256, 4) void ktp(
    const float* __restrict__ na, const float* __restrict__ eemb,
    const float* __restrict__ sh, const int* __restrict__ ei,
    const float* __restrict__ fc1w, const float* __restrict__ fc1b,
    const float* __restrict__ fc2w, const float* __restrict__ fc2b,
    float* __restrict__ out_tp)
{
    constexpr int NCOL = (L == 0 ? 1280 : L == 1 ? 1664 : L == 2 ? 2048 : 3328);
    constexpr int DIN  = (L == 0 ? 32 : L == 1 ? 56 : L == 2 ? 80 : 112);
    constexpr int DOUT = (L == 0 ? 56 : L == 1 ? 80 : 112);
    constexpr int NP   = (L == 0 ? 2 : L == 1 ? 5 : L == 2 ? 8 : 10);
    constexpr int NG   = NCOL / 4;            // float4 column groups
    constexpr int NKK  = (NG + 255) / 256;    // chunks of 256 groups
    const PathT* PT = (L == 0 ? PATHS0 : L == 1 ? PATHS1 : L == 2 ? PATHS2 : PATHS3);

    __shared__ float eac[8][96];
    __shared__ float hbuf[8][96];
    __shared__ float xs[8][112];
    __shared__ float shl[8][4];
    __shared__ float oacc[8][112];
    __shared__ int   sdn[8], ddn[8];

    int tid = threadIdx.x;
    int e0  = blockIdx.x * 8;
    if (tid < 8) { sdn[tid] = ei[e0 + tid]; ddn[tid] = ei[N_EDGES + e0 + tid]; }
    __syncthreads();

    for (int idx = tid; idx < 8 * 96; idx += 256) {
        int e = idx / 96, c = idx % 96;
        float v;
        if (c < 32)      v = eemb[(e0 + e) * 32 + c];
        else if (c < 64) v = na[sdn[e] * 112 + (c - 32)];
        else             v = na[ddn[e] * 112 + (c - 64)];
        eac[e][c] = v;
    }
    for (int idx = tid; idx < 8 * DIN; idx += 256) {
        int e = idx / DIN, d = idx % DIN;
        xs[e][d] = na[sdn[e] * 112 + d];
    }
    if (tid < 32) { int e = tid >> 2, q = tid & 3; shl[e][q] = sh[(e0 + e) * 4 + q]; }
    for (int idx = tid; idx < 8 * 112; idx += 256) { oacc[idx / 112][idx % 112] = 0.f; }
    __syncthreads();

    // h = relu(eac @ fc1_w + fc1_b)
    for (int oi = tid; oi < 8 * 96; oi += 256) {
        int e = oi / 96, c = oi % 96;
        float s = fc1b[c];
#pragma unroll 8
        for (int f = 0; f < 96; ++f) s += eac[e][f] * fc1w[f * 96 + c];
        hbuf[e][c] = fmaxf(s, 0.f);
    }
    __syncthreads();

    // fc2 + TP, chunked: thread owns columns [4g, 4g+4), g = tid + 256*kk
    for (int kk = 0; kk < NKK; ++kk) {
        int g = tid + 256 * kk;
        if (g < NG) {
            const int j0 = 4 * g;
            float4 b4 = *(const float4*)(fc2b + j0);
            float acc[4][8];
#pragma unroll
            for (int e = 0; e < 8; ++e) {
                acc[0][e] = b4.x; acc[1][e] = b4.y; acc[2][e] = b4.z; acc[3][e] = b4.w;
            }
            const float* wp = fc2w + j0;
#pragma unroll 4
            for (int c4 = 0; c4 < 24; ++c4) {
                float4 w0 = *(const float4*)(wp + (size_t)(4 * c4 + 0) * NCOL);
                float4 w1 = *(const float4*)(wp + (size_t)(4 * c4 + 1) * NCOL);
                float4 w2 = *(const float4*)(wp + (size_t)(4 * c4 + 2) * NCOL);
                float4 w3 = *(const float4*)(wp + (size_t)(4 * c4 + 3) * NCOL);
#pragma unroll
                for (int e = 0; e < 8; ++e) {
                    float4 h4 = *(const float4*)(&hbuf[e][4 * c4]);
                    acc[0][e] += h4.x * w0.x + h4.y * w1.x + h4.z * w2.x + h4.w * w3.x;
                    acc[1][e] += h4.x * w0.y + h4.y * w1.y + h4.z * w2.y + h4.w * w3.y;
                    acc[2][e] += h4.x * w0.z + h4.y * w1.z + h4.z * w2.z + h4.w * w3.z;
                    acc[3][e] += h4.x * w0.w + h4.y * w1.w + h4.z * w2.w + h4.w * w3.w;
                }
            }

            // TP epilogue for the 4 columns j0..j0+3
#pragma unroll
            for (int q = 0; q < 4; ++q) {
                int j = j0 + q;
                int p = 0;
#pragma unroll
                for (int pp = 1; pp < NP; ++pp) if (j >= PT[pp].woff) p = pp;
                PathT P  = PT[p];
                int rel  = j - P.woff;
                int u    = rel >> P.l2m3;
                int w3i  = rel & ((1 << P.l2m3) - 1);
                if (P.kind == 0) {
#pragma unroll
                    for (int e = 0; e < 8; ++e)
                        atomicAdd(&oacc[e][P.outoff + w3i], P.coef * xs[e][P.inoff + u] * acc[q][e]);
                } else if (P.kind == 1) {
#pragma unroll
                    for (int e = 0; e < 8; ++e) {
                        float t = P.coef * xs[e][P.inoff + u] * acc[q][e];
                        atomicAdd(&oacc[e][P.outoff + 3 * w3i + 0], t * shl[e][1]);
                        atomicAdd(&oacc[e][P.outoff + 3 * w3i + 1], t * shl[e][2]);
                        atomicAdd(&oacc[e][P.outoff + 3 * w3i + 2], t * shl[e][3]);
                    }
                } else if (P.kind == 2) {
#pragma unroll
                    for (int e = 0; e < 8; ++e) {
                        float t = P.coef * acc[q][e];
                        atomicAdd(&oacc[e][P.outoff + 3 * w3i + 0], t * xs[e][P.inoff + 3 * u + 0]);
                        atomicAdd(&oacc[e][P.outoff + 3 * w3i + 1], t * xs[e][P.inoff + 3 * u + 1]);
                        atomicAdd(&oacc[e][P.outoff + 3 * w3i + 2], t * xs[e][P.inoff + 3 * u + 2]);
                    }
                } else if (P.kind == 3) {
#pragma unroll
                    for (int e = 0; e < 8; ++e) {
                        float s = xs[e][P.inoff + 3 * u + 0] * shl[e][1]
                                + xs[e][P.inoff + 3 * u + 1] * shl[e][2]
                                + xs[e][P.inoff + 3 * u + 2] * shl[e][3];
                        atomicAdd(&oacc[e][P.outoff + w3i], P.coef * s * acc[q][e]);
                    }
                } else {
#pragma unroll
                    for (int e = 0; e < 8; ++e) {
                        float x0 = xs[e][P.inoff + 3 * u + 0];
                        float x1 = xs[e][P.inoff + 3 * u + 1];
                        float x2 = xs[e][P.inoff + 3 * u + 2];
                        float y0 = shl[e][1], y1 = shl[e][2], y2 = shl[e][3];
                        float t  = P.coef * acc[q][e];
                        atomicAdd(&oacc[e][P.outoff + 3 * w3i + 0], t * (x1 * y2 - x2 * y1));
                        atomicAdd(&oacc[e][P.outoff + 3 * w3i + 1], t * (x2 * y0 - x0 * y2));
                        atomicAdd(&oacc[e][P.outoff + 3 * w3i + 2], t * (x0 * y1 - x1 * y0));
                    }
                }
            }
        }
    }
    __syncthreads();

    // scatter to out_tp[dst]
    for (int idx = tid; idx < 8 * DOUT; idx += 256) {
        int e = idx / DOUT, d = idx % DOUT;
        unsafeAtomicAdd(&out_tp[ddn[e] * 112 + d], oacc[e][d]);
    }
}

// ---------------------------------------------------------------------------
// K4: out = out_tp / max(cnt,1) + pad(node_attr)
// ---------------------------------------------------------------------------
__global__ void knodeout(const float* __restrict__ tp, const int* __restrict__ cnt,
                         const float* __restrict__ na, float* __restrict__ outb,
                         int din, int dout)
{
    int idx = blockIdx.x * 256 + threadIdx.x;
    if (idx >= N_NODES * dout) return;
    int n = idx / dout, d = idx % dout;
    float c = fmaxf((float)cnt[n], 1.f);
    float v = tp[n * 112 + d] / c + (d < din ? na[n * 112 + d] : 0.f);
    outb[n * 112 + d] = v;
}

// ---------------------------------------------------------------------------
// K5: per-dim sums (one block per output dim)
// ---------------------------------------------------------------------------
__global__ void kstats(const float* __restrict__ outb, float* __restrict__ sums,
                       float* __restrict__ sumsq)
{
    int d = blockIdx.x;
    int tid = threadIdx.x;
    float s = 0.f, s2 = 0.f;
    for (int n = tid; n < N_NODES; n += 256) {
        float v = outb[n * 112 + d];
        s += v; s2 += v * v;
    }
    __shared__ float r1[256], r2[256];
    r1[tid] = s; r2[tid] = s2;
    __syncthreads();
    for (int o = 128; o > 0; o >>= 1) {
        if (tid < o) { r1[tid] += r1[tid + o]; r2[tid] += r2[tid + o]; }
        __syncthreads();
    }
    if (tid == 0) { sums[d] = r1[0]; sumsq[d] = r2[0]; }
}

// ---------------------------------------------------------------------------
// K6: finalize batchnorm scale/bias per dim
// ---------------------------------------------------------------------------
__global__ void kfin(const float* __restrict__ sums, const float* __restrict__ sumsq,
                     float* __restrict__ scale, float* __restrict__ bias,
                     int dout, int vend)
{
    int d = threadIdx.x;
    if (d >= dout) return;
    const float invN = 1.f / (float)N_NODES;
    if (d < 32 || d >= vend) {
        float m   = sums[d] * invN;
        float var = sumsq[d] * invN - m * m;
        scale[d] = rsqrtf(var + 1e-5f);
        bias[d]  = m;
    } else {
        int b = 32 + ((d - 32) / 3) * 3;
        float n2 = (sumsq[b] + sumsq[b + 1] + sumsq[b + 2]) * (invN / 3.f);
        scale[d] = rsqrtf(n2 + 1e-5f);
        bias[d]  = 0.f;
    }
}

// ---------------------------------------------------------------------------
// K7: apply normalization
// ---------------------------------------------------------------------------
__global__ void kapply(const float* __restrict__ outb, const float* __restrict__ scale,
                       const float* __restrict__ bias, float* __restrict__ dst, int dout)
{
    int idx = blockIdx.x * 256 + threadIdx.x;
    if (idx >= N_NODES * dout) return;
    int n = idx / dout, d = idx % dout;
    dst[n * 112 + d] = (outb[n * 112 + d] - bias[d]) * scale[d];
}

// ---------------------------------------------------------------------------
extern "C" void kernel_launch(void* const* d_in, const int* in_sizes, int n_in,
                              void* d_out, int out_size, void* d_ws, size_t ws_size,
                              hipStream_t stream)
{
    (void)in_sizes; (void)n_in; (void)out_size; (void)ws_size;
    const float* x     = (const float*)d_in[0];
    const float* pos   = (const float*)d_in[1];
    const float* sigma = (const float*)d_in[2];
    const float* eain  = (const float*)d_in[3];
    const float* nw1 = (const float*)d_in[4];  const float* nb1 = (const float*)d_in[5];
    const float* nw2 = (const float*)d_in[6];  const float* nb2 = (const float*)d_in[7];
    const float* ew1 = (const float*)d_in[8];  const float* eb1 = (const float*)d_in[9];
    const float* ew2 = (const float*)d_in[10]; const float* eb2 = (const float*)d_in[11];
    const float* fc1w = (const float*)d_in[12];
    const float* fc1b = (const float*)d_in[13];
    const float* fc2w[4] = {(const float*)d_in[14], (const float*)d_in[16],
                            (const float*)d_in[18], (const float*)d_in[20]};
    const float* fc2b[4] = {(const float*)d_in[15], (const float*)d_in[17],
                            (const float*)d_in[19], (const float*)d_in[21]};
    const int* ei = (const int*)d_in[22];

    float* ws   = (float*)d_ws;
    float* semb = ws + 0;            // N*32
    float* na   = ws + 320000;       // N*112
    float* outb = ws + 1440000;      // N*112
    float* tp   = ws + 2560000;      // N*112
    float* sh   = ws + 3680000;      // E*4
    float* eemb = ws + 3840000;      // E*32
    int*   cnt  = (int*)(ws + 5120000); // N
    float* sums  = ws + 5130000;     // 112
    float* sumsq = ws + 5130112;     // 112
    float* scale = ws + 5130224;     // 112
    float* bias  = ws + 5130336;     // 112
    float* out = (float*)d_out;

    hipMemsetAsync(cnt, 0, N_NODES * sizeof(int), stream);
    ksemb<<<(N_NODES + 255) / 256, 256, 0, stream>>>(sigma, semb);
    knodemlp<<<N_NODES / 8, 256, 0, stream>>>(x, semb, nw1, nb1, nw2, nb2, na);
    kedgepre<<<N_EDGES / 8, 256, 0, stream>>>(pos, eain, semb, ei, ew1, eb1, ew2, eb2,
                                              sh, eemb, cnt);

    const int DIN_[4]  = {32, 56, 80, 112};
    const int DOUT_[4] = {56, 80, 112, 112};
    const int VEND_[4] = {56, 80, 80, 80};
    for (int L = 0; L < 4; ++L) {
        hipMemsetAsync(tp, 0, (size_t)N_NODES * 112 * sizeof(float), stream);
        switch (L) {
        case 0: ktp<0><<<N_EDGES / 8, 256, 0, stream>>>(na, eemb, sh, ei, fc1w + 0 * 9216,
                    fc1b + 0 * 96, fc2w[0], fc2b[0], tp); break;
        case 1: ktp<1><<<N_EDGES / 8, 256, 0, stream>>>(na, eemb, sh, ei, fc1w + 1 * 9216,
                    fc1b + 1 * 96, fc2w[1], fc2b[1], tp); break;
        case 2: ktp<2><<<N_EDGES / 8, 256, 0, stream>>>(na, eemb, sh, ei, fc1w + 2 * 9216,
                    fc1b + 2 * 96, fc2w[2], fc2b[2], tp); break;
        default: ktp<3><<<N_EDGES / 8, 256, 0, stream>>>(na, eemb, sh, ei, fc1w + 3 * 9216,
                    fc1b + 3 * 96, fc2w[3], fc2b[3], tp); break;
        }
        knodeout<<<(N_NODES * DOUT_[L] + 255) / 256, 256, 0, stream>>>(tp, cnt, na, outb,
                                                                       DIN_[L], DOUT_[L]);
        kstats<<<DOUT_[L], 256, 0, stream>>>(outb, sums, sumsq);
        kfin<<<1, 128, 0, stream>>>(sums, sumsq, scale, bias, DOUT_[L], VEND_[L]);
        float* dstp = (L == 3) ? out : na;
        kapply<<<(N_NODES * DOUT_[L] + 255) / 256, 256, 0, stream>>>(outb, scale, bias,
                                                                     dstp, DOUT_[L]);
    }
}

// Round 4
// 2900.813 us; speedup vs baseline: 1.2708x; 1.1190x over previous
//
#include <hip/hip_runtime.h>
#include <math.h>

#define N_NODES 10000
#define N_EDGES 40000

typedef __attribute__((ext_vector_type(8))) short bf16x8;
typedef __attribute__((ext_vector_type(4))) float f32x4;

__device__ inline unsigned short f2bf(float f) {
    unsigned u = __float_as_uint(f);
    return (unsigned short)((u + 0x7FFFu + ((u >> 16) & 1u)) >> 16);
}

// ---------------------------------------------------------------------------
// Tensor-product path tables. kind: 0=(0,0,0) 1=(0,1,1) 2=(1,0,1) 3=(1,1,0) 4=(1,1,1)
// ---------------------------------------------------------------------------
struct PathT { int woff, m1, l2m3, inoff, outoff, kind; float coef; };

__device__ const PathT PATHS0[2] = {
  {   0,32,5, 0, 0,0, 0.17677670f},
  {1024,32,3, 0,32,1, 0.17677670f},
};
__device__ const PathT PATHS1[5] = {
  {   0,32,5, 0, 0,0, 0.15811388f},
  {1024,32,3, 0,32,1, 0.15811388f},
  {1280, 8,3,32,32,2, 0.15811388f},
  {1344, 8,5,32, 0,3, 0.09128709f},
  {1600, 8,3,32,56,4, 0.25f},
};
__device__ const PathT PATHS2[8] = {
  {   0,32,5, 0, 0,0, 0.15811388f},
  {1024,32,3, 0,32,1, 0.14433757f},
  {1280, 8,3,32,32,2, 0.14433757f},
  {1344, 8,5,32, 0,3, 0.09128709f},
  {1600, 8,3,32,56,4, 0.17677670f},
  {1664, 8,3,56,56,2, 0.25f},
  {1728, 8,3,56,32,4, 0.10206207f},
  {1792, 8,5,56,80,3, 0.20412415f},
};
__device__ const PathT PATHS3[10] = {
  {   0,32,5, 0, 0,0, 0.15811388f},
  {1024,32,3, 0,32,1, 0.14433757f},
  {1280, 8,3,32,32,2, 0.14433757f},
  {1344, 8,5,32, 0,3, 0.09128709f},
  {1600, 8,3,32,56,4, 0.10206207f},
  {1664, 8,3,56,56,2, 0.14433757f},
  {1728, 8,3,56,32,4, 0.10206207f},
  {1792, 8,5,56,80,3, 0.09128709f},
  {2048,32,5,80,80,0, 0.15811388f},
  {3072,32,3,80,56,1, 0.14433757f},
};

// ---------------------------------------------------------------------------
// kpack: f32 weight [96][ncol] -> bf16 B-fragment-packed layout.
// frag index = (jt*3 + t)*64 + lane ; element i: w[32t + 8*(lane>>4) + i][jt*16 + (lane&15)]
// ---------------------------------------------------------------------------
__global__ void kpack(const float* __restrict__ w, int ncol, unsigned short* __restrict__ dst)
{
    int idx = blockIdx.x * 256 + threadIdx.x;
    if (idx >= ncol * 12) return;          // (ncol/16)*3*64
    int lane = idx & 63;
    int rest = idx >> 6;
    int t  = rest % 3;
    int jt = rest / 3;
    int n  = jt * 16 + (lane & 15);
    int k0 = 32 * t + 8 * (lane >> 4);
    bf16x8 v;
#pragma unroll
    for (int i = 0; i < 8; ++i) v[i] = (short)f2bf(w[(size_t)(k0 + i) * ncol + n]);
    *(bf16x8*)(dst + (size_t)idx * 8) = v;
}

// ---------------------------------------------------------------------------
// K0: timestep embedding per node
// ---------------------------------------------------------------------------
__global__ void ksemb(const float* __restrict__ sigma, float* __restrict__ semb)
{
    int n = blockIdx.x * 256 + threadIdx.x;
    if (n >= N_NODES) return;
    float t = logf(sigma[n] * (1.0f / 0.031415926535897934f)) * 2171.4724095f;
#pragma unroll
    for (int j = 0; j < 16; ++j) {
        float f = expf(-0.61402269f * (float)j);
        float a = t * f;
        semb[n * 32 + j]      = sinf(a);
        semb[n * 32 + 16 + j] = cosf(a);
    }
}

// ---------------------------------------------------------------------------
// K1: node MLP
// ---------------------------------------------------------------------------
__global__ void knodemlp(const float* __restrict__ x, const float* __restrict__ semb,
                         const float* __restrict__ w1, const float* __restrict__ b1,
                         const float* __restrict__ w2, const float* __restrict__ b2,
                         float* __restrict__ na)
{
    __shared__ float xin[8][106];
    __shared__ float h1[8][32];
    int tid = threadIdx.x;
    int n0  = blockIdx.x * 8;
    for (int idx = tid; idx < 8 * 106; idx += 256) {
        int e = idx / 106, q = idx % 106;
        int n = n0 + e;
        float v = 0.f;
        if (n < N_NODES) v = (q < 74) ? x[n * 74 + q] : semb[n * 32 + (q - 74)];
        xin[e][q] = v;
    }
    __syncthreads();
    {
        int e = tid / 32, c = tid % 32;
        float s = b1[c];
        for (int f = 0; f < 106; ++f) s += xin[e][f] * w1[f * 32 + c];
        h1[e][c] = fmaxf(s, 0.f);
    }
    __syncthreads();
    {
        int e = tid / 32, c = tid % 32;
        int n = n0 + e;
        if (n < N_NODES) {
            float s = b2[c];
#pragma unroll
            for (int f = 0; f < 32; ++f) s += h1[e][f] * w2[f * 32 + c];
            na[n * 112 + c] = s;
        }
    }
}

// ---------------------------------------------------------------------------
// K2: per-edge precompute
// ---------------------------------------------------------------------------
__global__ void kedgepre(const float* __restrict__ pos, const float* __restrict__ eattr_in,
                         const float* __restrict__ semb, const int* __restrict__ ei,
                         const float* __restrict__ w1, const float* __restrict__ b1,
                         const float* __restrict__ w2, const float* __restrict__ b2,
                         float* __restrict__ sh, float* __restrict__ eemb, int* __restrict__ cnt)
{
    __shared__ float ea[8][86];
    __shared__ float h1[8][32];
    __shared__ float dl[8];
    __shared__ int   sl[8];
    int tid = threadIdx.x;
    int e0  = blockIdx.x * 8;
    if (tid < 8) {
        int ge = e0 + tid;
        int s = ei[ge], d = ei[N_EDGES + ge];
        sl[tid] = s;
        float dx = pos[d * 3 + 0] - pos[s * 3 + 0];
        float dy = pos[d * 3 + 1] - pos[s * 3 + 1];
        float dz = pos[d * 3 + 2] - pos[s * 3 + 2];
        float dist = sqrtf(dx * dx + dy * dy + dz * dz);
        dist = fmaxf(dist, 1e-6f);
        dl[tid] = dist;
        float inv = 1.7320508f / dist;
        sh[ge * 4 + 0] = 1.f;
        sh[ge * 4 + 1] = dx * inv;
        sh[ge * 4 + 2] = dy * inv;
        sh[ge * 4 + 3] = dz * inv;
        atomicAdd(&cnt[d], 1);
    }
    __syncthreads();
    for (int idx = tid; idx < 8 * 86; idx += 256) {
        int e = idx / 86, q = idx % 86;
        int ge = e0 + e;
        float v;
        if (q < 4)       v = eattr_in[ge * 4 + q];
        else if (q < 36) v = semb[sl[e] * 32 + (q - 4)];
        else {
            int qq = q - 36;
            float off = 5.f * (float)qq / 49.f;
            float dd  = dl[e] - off;
            v = expf(-48.02f * dd * dd);
        }
        ea[e][q] = v;
    }
    __syncthreads();
    {
        int e = tid / 32, c = tid % 32;
        float s = b1[c];
        for (int f = 0; f < 86; ++f) s += ea[e][f] * w1[f * 32 + c];
        h1[e][c] = fmaxf(s, 0.f);
    }
    __syncthreads();
    {
        int e = tid / 32, c = tid % 32;
        float s = b2[c];
#pragma unroll
        for (int f = 0; f < 32; ++f) s += h1[e][f] * w2[f * 32 + c];
        eemb[(e0 + e) * 32 + c] = s;
    }
}

// ---------------------------------------------------------------------------
// K3: fused fc1(f32) -> fc2(bf16 MFMA) -> TP epilogue -> scatter.
// 32 edges/block, 256 threads = 4 waves. Wave w handles col-tile jt=it*4+w.
// A (h, 32x96) in register fragments; B from packed bf16 weights (global).
// C frag: col=lane&15 (fc2 col), row=(lane>>4)*4+reg (edge in 16-tile).
// ---------------------------------------------------------------------------
template <int L>
__global__ __launch_bounds__(256, 3) void ktp(
    const float* __restrict__ na, const float* __restrict__ eemb,
    const float* __restrict__ sh, const int* __restrict__ ei,
    const float* __restrict__ fc1w, const float* __restrict__ fc1b,
    const unsigned short* __restrict__ wpk, const float* __restrict__ fc2b,
    float* __restrict__ out_tp)
{
    constexpr int NCOL = (L == 0 ? 1280 : L == 1 ? 1664 : L == 2 ? 2048 : 3328);
    constexpr int DIN  = (L == 0 ? 32 : L == 1 ? 56 : L == 2 ? 80 : 112);
    constexpr int DOUT = (L == 0 ? 56 : L == 1 ? 80 : 112);
    constexpr int NP   = (L == 0 ? 2 : L == 1 ? 5 : L == 2 ? 8 : 10);
    constexpr int ITERS = NCOL / 64;
    const PathT* PT = (L == 0 ? PATHS0 : L == 1 ? PATHS1 : L == 2 ? PATHS2 : PATHS3);

    // uni: [0..3071] eac(32x96) ; [3072..6271] hbuf(32x100 padded) ; later oacc(32x113) @0
    __shared__ float uni[6272];
    __shared__ float xs[32 * 113];
    __shared__ float shl4[32 * 4];
    __shared__ int   sdn[32], ddn[32];

    const int tid  = threadIdx.x;
    const int lane = tid & 63;
    const int wid  = tid >> 6;
    const int e0   = blockIdx.x * 32;

    if (tid < 32) { sdn[tid] = ei[e0 + tid]; ddn[tid] = ei[N_EDGES + e0 + tid]; }
    __syncthreads();

    for (int idx = tid; idx < 32 * 96; idx += 256) {
        int e = idx / 96, c = idx % 96;
        float v;
        if (c < 32)      v = eemb[(e0 + e) * 32 + c];
        else if (c < 64) v = na[sdn[e] * 112 + (c - 32)];
        else             v = na[ddn[e] * 112 + (c - 64)];
        uni[idx] = v;
    }
    for (int idx = tid; idx < 32 * DIN; idx += 256) {
        int e = idx / DIN, d = idx % DIN;
        xs[e * 113 + d] = na[sdn[e] * 112 + d];
    }
    if (tid < 128) shl4[tid] = sh[e0 * 4 + tid];
    __syncthreads();

    // fc1: h = relu(eac @ fc1w + b), write to hbuf (row pad 100)
    for (int oi = tid; oi < 32 * 96; oi += 256) {
        int e = oi / 96, c = oi % 96;
        float s = fc1b[c];
#pragma unroll 8
        for (int f = 0; f < 96; ++f) s += uni[e * 96 + f] * fc1w[f * 96 + c];
        uni[3072 + e * 100 + c] = fmaxf(s, 0.f);
    }
    __syncthreads();

    // A fragments: afrag[mt][t], lane holds h[16mt + (lane&15)][32t + 8*(lane>>4) + i]
    bf16x8 afrag[2][3];
    {
        int m = lane & 15, g = lane >> 4;
#pragma unroll
        for (int mt = 0; mt < 2; ++mt)
#pragma unroll
        for (int t = 0; t < 3; ++t) {
            const float* hp = &uni[3072 + (16 * mt + m) * 100 + 32 * t + 8 * g];
            f32x4 h0 = *(const f32x4*)hp;
            f32x4 h1 = *(const f32x4*)(hp + 4);
            bf16x8 a;
            a[0] = (short)f2bf(h0.x); a[1] = (short)f2bf(h0.y);
            a[2] = (short)f2bf(h0.z); a[3] = (short)f2bf(h0.w);
            a[4] = (short)f2bf(h1.x); a[5] = (short)f2bf(h1.y);
            a[6] = (short)f2bf(h1.z); a[7] = (short)f2bf(h1.w);
            afrag[mt][t] = a;
        }
    }
    // preload sh components for this lane's 8 epilogue edges
    float sy1[8], sy2[8], sy3[8];
#pragma unroll
    for (int mt = 0; mt < 2; ++mt)
#pragma unroll
    for (int r = 0; r < 4; ++r) {
        int e = mt * 16 + (lane >> 4) * 4 + r;
        sy1[mt * 4 + r] = shl4[e * 4 + 1];
        sy2[mt * 4 + r] = shl4[e * 4 + 2];
        sy3[mt * 4 + r] = shl4[e * 4 + 3];
    }
    __syncthreads();                       // all reads of hbuf done
    for (int idx = tid; idx < 32 * 113; idx += 256) uni[idx] = 0.f;   // oacc := 0
    __syncthreads();

    // fc2 via MFMA + fused TP epilogue
    const bf16x8* wp = (const bf16x8*)wpk;
    const int ebase = (lane >> 4) * 4;
    for (int it = 0; it < ITERS; ++it) {
        const int jt = it * 4 + wid;
        const int j  = jt * 16 + (lane & 15);
        bf16x8 bfr[3];
#pragma unroll
        for (int t = 0; t < 3; ++t) bfr[t] = wp[(jt * 3 + t) * 64 + lane];
        float bias = fc2b[j];
        f32x4 acc[2];
        acc[0] = (f32x4){bias, bias, bias, bias};
        acc[1] = acc[0];
#pragma unroll
        for (int t = 0; t < 3; ++t) {
            acc[0] = __builtin_amdgcn_mfma_f32_16x16x32_bf16(afrag[0][t], bfr[t], acc[0], 0, 0, 0);
            acc[1] = __builtin_amdgcn_mfma_f32_16x16x32_bf16(afrag[1][t], bfr[t], acc[1], 0, 0, 0);
        }

        // decode path for column j (uniform within each 16-lane group)
        int p = 0;
#pragma unroll
        for (int pp = 1; pp < NP; ++pp) if (j >= PT[pp].woff) p = pp;
        PathT P  = PT[p];
        int rel  = j - P.woff;
        int u    = rel >> P.l2m3;
        int w3i  = rel & ((1 << P.l2m3) - 1);

#pragma unroll
        for (int mt = 0; mt < 2; ++mt) {
#pragma unroll
            for (int r = 0; r < 4; ++r) {
                int e = mt * 16 + ebase + r;
                float v = acc[mt][r];
                float* oa = &uni[e * 113];
                const float* xe = &xs[e * 113];
                int si = mt * 4 + r;
                if (P.kind == 0) {
                    atomicAdd(&oa[P.outoff + w3i], P.coef * xe[P.inoff + u] * v);
                } else if (P.kind == 1) {
                    float t = P.coef * xe[P.inoff + u] * v;
                    atomicAdd(&oa[P.outoff + 3 * w3i + 0], t * sy1[si]);
                    atomicAdd(&oa[P.outoff + 3 * w3i + 1], t * sy2[si]);
                    atomicAdd(&oa[P.outoff + 3 * w3i + 2], t * sy3[si]);
                } else if (P.kind == 2) {
                    float t = P.coef * v;
                    atomicAdd(&oa[P.outoff + 3 * w3i + 0], t * xe[P.inoff + 3 * u + 0]);
                    atomicAdd(&oa[P.outoff + 3 * w3i + 1], t * xe[P.inoff + 3 * u + 1]);
                    atomicAdd(&oa[P.outoff + 3 * w3i + 2], t * xe[P.inoff + 3 * u + 2]);
                } else if (P.kind == 3) {
                    float s = xe[P.inoff + 3 * u + 0] * sy1[si]
                            + xe[P.inoff + 3 * u + 1] * sy2[si]
                            + xe[P.inoff + 3 * u + 2] * sy3[si];
                    atomicAdd(&oa[P.outoff + w3i], P.coef * s * v);
                } else {
                    float x0 = xe[P.inoff + 3 * u + 0];
                    float x1 = xe[P.inoff + 3 * u + 1];
                    float x2 = xe[P.inoff + 3 * u + 2];
                    float t  = P.coef * v;
                    atomicAdd(&oa[P.outoff + 3 * w3i + 0], t * (x1 * sy3[si] - x2 * sy2[si]));
                    atomicAdd(&oa[P.outoff + 3 * w3i + 1], t * (x2 * sy1[si] - x0 * sy3[si]));
                    atomicAdd(&oa[P.outoff + 3 * w3i + 2], t * (x0 * sy2[si] - x1 * sy1[si]));
                }
            }
        }
    }
    __syncthreads();

    // scatter to out_tp[dst]
    for (int idx = tid; idx < 32 * DOUT; idx += 256) {
        int e = idx / DOUT, d = idx % DOUT;
        unsafeAtomicAdd(&out_tp[ddn[e] * 112 + d], uni[e * 113 + d]);
    }
}

// ---------------------------------------------------------------------------
// K4: out = out_tp / max(cnt,1) + pad(node_attr)
// ---------------------------------------------------------------------------
__global__ void knodeout(const float* __restrict__ tp, const int* __restrict__ cnt,
                         const float* __restrict__ na, float* __restrict__ outb,
                         int din, int dout)
{
    int idx = blockIdx.x * 256 + threadIdx.x;
    if (idx >= N_NODES * dout) return;
    int n = idx / dout, d = idx % dout;
    float c = fmaxf((float)cnt[n], 1.f);
    float v = tp[n * 112 + d] / c + (d < din ? na[n * 112 + d] : 0.f);
    outb[n * 112 + d] = v;
}

// ---------------------------------------------------------------------------
// K5: per-dim sums
// ---------------------------------------------------------------------------
__global__ void kstats(const float* __restrict__ outb, float* __restrict__ sums,
                       float* __restrict__ sumsq)
{
    int d = blockIdx.x;
    int tid = threadIdx.x;
    float s = 0.f, s2 = 0.f;
    for (int n = tid; n < N_NODES; n += 256) {
        float v = outb[n * 112 + d];
        s += v; s2 += v * v;
    }
    __shared__ float r1[256], r2[256];
    r1[tid] = s; r2[tid] = s2;
    __syncthreads();
    for (int o = 128; o > 0; o >>= 1) {
        if (tid < o) { r1[tid] += r1[tid + o]; r2[tid] += r2[tid + o]; }
        __syncthreads();
    }
    if (tid == 0) { sums[d] = r1[0]; sumsq[d] = r2[0]; }
}

// ---------------------------------------------------------------------------
// K6: finalize batchnorm scale/bias per dim
// ---------------------------------------------------------------------------
__global__ void kfin(const float* __restrict__ sums, const float* __restrict__ sumsq,
                     float* __restrict__ scale, float* __restrict__ bias,
                     int dout, int vend)
{
    int d = threadIdx.x;
    if (d >= dout) return;
    const float invN = 1.f / (float)N_NODES;
    if (d < 32 || d >= vend) {
        float m   = sums[d] * invN;
        float var = sumsq[d] * invN - m * m;
        scale[d] = rsqrtf(var + 1e-5f);
        bias[d]  = m;
    } else {
        int b = 32 + ((d - 32) / 3) * 3;
        float n2 = (sumsq[b] + sumsq[b + 1] + sumsq[b + 2]) * (invN / 3.f);
        scale[d] = rsqrtf(n2 + 1e-5f);
        bias[d]  = 0.f;
    }
}

// ---------------------------------------------------------------------------
// K7: apply normalization
// ---------------------------------------------------------------------------
__global__ void kapply(const float* __restrict__ outb, const float* __restrict__ scale,
                       const float* __restrict__ bias, float* __restrict__ dst, int dout)
{
    int idx = blockIdx.x * 256 + threadIdx.x;
    if (idx >= N_NODES * dout) return;
    int n = idx / dout, d = idx % dout;
    dst[n * 112 + d] = (outb[n * 112 + d] - bias[d]) * scale[d];
}

// ---------------------------------------------------------------------------
extern "C" void kernel_launch(void* const* d_in, const int* in_sizes, int n_in,
                              void* d_out, int out_size, void* d_ws, size_t ws_size,
                              hipStream_t stream)
{
    (void)in_sizes; (void)n_in; (void)out_size; (void)ws_size;
    const float* x     = (const float*)d_in[0];
    const float* pos   = (const float*)d_in[1];
    const float* sigma = (const float*)d_in[2];
    const float* eain  = (const float*)d_in[3];
    const float* nw1 = (const float*)d_in[4];  const float* nb1 = (const float*)d_in[5];
    const float* nw2 = (const float*)d_in[6];  const float* nb2 = (const float*)d_in[7];
    const float* ew1 = (const float*)d_in[8];  const float* eb1 = (const float*)d_in[9];
    const float* ew2 = (const float*)d_in[10]; const float* eb2 = (const float*)d_in[11];
    const float* fc1w = (const float*)d_in[12];
    const float* fc1b = (const float*)d_in[13];
    const float* fc2w[4] = {(const float*)d_in[14], (const float*)d_in[16],
                            (const float*)d_in[18], (const float*)d_in[20]};
    const float* fc2b[4] = {(const float*)d_in[15], (const float*)d_in[17],
                            (const float*)d_in[19], (const float*)d_in[21]};
    const int* ei = (const int*)d_in[22];

    float* ws   = (float*)d_ws;
    float* semb = ws + 0;            // N*32
    float* na   = ws + 320000;       // N*112
    float* outb = ws + 1440000;      // N*112
    float* tp   = ws + 2560000;      // N*112
    float* sh   = ws + 3680000;      // E*4
    float* eemb = ws + 3840000;      // E*32
    int*   cnt  = (int*)(ws + 5120000); // N
    float* sums  = ws + 5130000;     // 112
    float* sumsq = ws + 5130112;     // 112
    float* scale = ws + 5130224;     // 112
    float* bias  = ws + 5130336;     // 112
    unsigned short* wpk = (unsigned short*)(ws + 5131008);  // 798720 bf16
    float* out = (float*)d_out;

    const int NCOL_[4] = {1280, 1664, 2048, 3328};
    const size_t WOFF_[4] = {0, 122880, 282624, 479232};   // 96*NCOL cumulative

    hipMemsetAsync(cnt, 0, N_NODES * sizeof(int), stream);
    for (int L = 0; L < 4; ++L)
        kpack<<<(NCOL_[L] * 12 + 255) / 256, 256, 0, stream>>>(fc2w[L], NCOL_[L], wpk + WOFF_[L]);
    ksemb<<<(N_NODES + 255) / 256, 256, 0, stream>>>(sigma, semb);
    knodemlp<<<N_NODES / 8, 256, 0, stream>>>(x, semb, nw1, nb1, nw2, nb2, na);
    kedgepre<<<N_EDGES / 8, 256, 0, stream>>>(pos, eain, semb, ei, ew1, eb1, ew2, eb2,
                                              sh, eemb, cnt);

    const int DIN_[4]  = {32, 56, 80, 112};
    const int DOUT_[4] = {56, 80, 112, 112};
    const int VEND_[4] = {56, 80, 80, 80};
    for (int L = 0; L < 4; ++L) {
        hipMemsetAsync(tp, 0, (size_t)N_NODES * 112 * sizeof(float), stream);
        switch (L) {
        case 0: ktp<0><<<N_EDGES / 32, 256, 0, stream>>>(na, eemb, sh, ei, fc1w + 0 * 9216,
                    fc1b + 0 * 96, wpk + WOFF_[0], fc2b[0], tp); break;
        case 1: ktp<1><<<N_EDGES / 32, 256, 0, stream>>>(na, eemb, sh, ei, fc1w + 1 * 9216,
                    fc1b + 1 * 96, wpk + WOFF_[1], fc2b[1], tp); break;
        case 2: ktp<2><<<N_EDGES / 32, 256, 0, stream>>>(na, eemb, sh, ei, fc1w + 2 * 9216,
                    fc1b + 2 * 96, wpk + WOFF_[2], fc2b[2], tp); break;
        default: ktp<3><<<N_EDGES / 32, 256, 0, stream>>>(na, eemb, sh, ei, fc1w + 3 * 9216,
                    fc1b + 3 * 96, wpk + WOFF_[3], fc2b[3], tp); break;
        }
        knodeout<<<(N_NODES * DOUT_[L] + 255) / 256, 256, 0, stream>>>(tp, cnt, na, outb,
                                                                       DIN_[L], DOUT_[L]);
        kstats<<<DOUT_[L], 256, 0, stream>>>(outb, sums, sumsq);
        kfin<<<1, 128, 0, stream>>>(sums, sumsq, scale, bias, DOUT_[L], VEND_[L]);
        float* dstp = (L == 3) ? out : na;
        kapply<<<(N_NODES * DOUT_[L] + 255) / 256, 256, 0, stream>>>(outb, scale, bias,
                                                                     dstp, DOUT_[L]);
    }
}

// Round 5
// 2824.955 us; speedup vs baseline: 1.3049x; 1.0269x over previous
//
#include <hip/hip_runtime.h>
#include <math.h>

#define N_NODES 10000
#define N_EDGES 40000

typedef __attribute__((ext_vector_type(8))) short bf16x8;
typedef __attribute__((ext_vector_type(4))) float f32x4;

__device__ inline unsigned short f2bf(float f) {
    unsigned u = __float_as_uint(f);
    return (unsigned short)((u + 0x7FFFu + ((u >> 16) & 1u)) >> 16);
}

// ---------------------------------------------------------------------------
// Compile-time tensor-product path tables.
// kind: 0=(0,0,0) 1=(0,1,1) 2=(1,0,1) 3=(1,1,0) 4=(1,1,1)
// All woff boundaries are multiples of 64 -> one wave-tile never straddles.
// ---------------------------------------------------------------------------
template <int L> struct PC;
template <> struct PC<0> {
    static constexpr int NP = 2;
    static constexpr int woff[3]  = {0, 1024, 1280};
    static constexpr int l2m3[2]  = {5, 3};
    static constexpr int inoff[2] = {0, 0};
    static constexpr int outoff[2]= {0, 32};
    static constexpr int kind[2]  = {0, 1};
    static constexpr float coef[2]= {0.17677670f, 0.17677670f};
};
template <> struct PC<1> {
    static constexpr int NP = 5;
    static constexpr int woff[6]  = {0, 1024, 1280, 1344, 1600, 1664};
    static constexpr int l2m3[5]  = {5, 3, 3, 5, 3};
    static constexpr int inoff[5] = {0, 0, 32, 32, 32};
    static constexpr int outoff[5]= {0, 32, 32, 0, 56};
    static constexpr int kind[5]  = {0, 1, 2, 3, 4};
    static constexpr float coef[5]= {0.15811388f, 0.15811388f, 0.15811388f, 0.09128709f, 0.25f};
};
template <> struct PC<2> {
    static constexpr int NP = 8;
    static constexpr int woff[9]  = {0, 1024, 1280, 1344, 1600, 1664, 1728, 1792, 2048};
    static constexpr int l2m3[8]  = {5, 3, 3, 5, 3, 3, 3, 5};
    static constexpr int inoff[8] = {0, 0, 32, 32, 32, 56, 56, 56};
    static constexpr int outoff[8]= {0, 32, 32, 0, 56, 56, 32, 80};
    static constexpr int kind[8]  = {0, 1, 2, 3, 4, 2, 4, 3};
    static constexpr float coef[8]= {0.15811388f, 0.14433757f, 0.14433757f, 0.09128709f,
                                     0.17677670f, 0.25f, 0.10206207f, 0.20412415f};
};
template <> struct PC<3> {
    static constexpr int NP = 10;
    static constexpr int woff[11] = {0, 1024, 1280, 1344, 1600, 1664, 1728, 1792, 2048, 3072, 3328};
    static constexpr int l2m3[10] = {5, 3, 3, 5, 3, 3, 3, 5, 5, 3};
    static constexpr int inoff[10]= {0, 0, 32, 32, 32, 56, 56, 56, 80, 80};
    static constexpr int outoff[10]={0, 32, 32, 0, 56, 56, 32, 80, 80, 56};
    static constexpr int kind[10] = {0, 1, 2, 3, 4, 2, 4, 3, 0, 1};
    static constexpr float coef[10]={0.15811388f, 0.14433757f, 0.14433757f, 0.09128709f,
                                     0.10206207f, 0.14433757f, 0.10206207f, 0.09128709f,
                                     0.15811388f, 0.14433757f};
};

// ---------------------------------------------------------------------------
// kpack: f32 weight [96][ncol] -> bf16 B-fragment-packed layout.
// frag index = (jt*3 + t)*64 + lane ; element i: w[32t + 8*(lane>>4) + i][jt*16 + (lane&15)]
// ---------------------------------------------------------------------------
__global__ void kpack(const float* __restrict__ w, int ncol, unsigned short* __restrict__ dst)
{
    int idx = blockIdx.x * 256 + threadIdx.x;
    if (idx >= ncol * 12) return;          // (ncol/16)*3*64
    int lane = idx & 63;
    int rest = idx >> 6;
    int t  = rest % 3;
    int jt = rest / 3;
    int n  = jt * 16 + (lane & 15);
    int k0 = 32 * t + 8 * (lane >> 4);
    bf16x8 v;
#pragma unroll
    for (int i = 0; i < 8; ++i) v[i] = (short)f2bf(w[(size_t)(k0 + i) * ncol + n]);
    *(bf16x8*)(dst + (size_t)idx * 8) = v;
}

// ---------------------------------------------------------------------------
// K0: timestep embedding per node
// ---------------------------------------------------------------------------
__global__ void ksemb(const float* __restrict__ sigma, float* __restrict__ semb)
{
    int n = blockIdx.x * 256 + threadIdx.x;
    if (n >= N_NODES) return;
    float t = logf(sigma[n] * (1.0f / 0.031415926535897934f)) * 2171.4724095f;
#pragma unroll
    for (int j = 0; j < 16; ++j) {
        float f = expf(-0.61402269f * (float)j);
        float a = t * f;
        semb[n * 32 + j]      = sinf(a);
        semb[n * 32 + 16 + j] = cosf(a);
    }
}

// ---------------------------------------------------------------------------
// K1: node MLP
// ---------------------------------------------------------------------------
__global__ void knodemlp(const float* __restrict__ x, const float* __restrict__ semb,
                         const float* __restrict__ w1, const float* __restrict__ b1,
                         const float* __restrict__ w2, const float* __restrict__ b2,
                         float* __restrict__ na)
{
    __shared__ float xin[8][106];
    __shared__ float h1[8][32];
    int tid = threadIdx.x;
    int n0  = blockIdx.x * 8;
    for (int idx = tid; idx < 8 * 106; idx += 256) {
        int e = idx / 106, q = idx % 106;
        int n = n0 + e;
        float v = 0.f;
        if (n < N_NODES) v = (q < 74) ? x[n * 74 + q] : semb[n * 32 + (q - 74)];
        xin[e][q] = v;
    }
    __syncthreads();
    {
        int e = tid / 32, c = tid % 32;
        float s = b1[c];
        for (int f = 0; f < 106; ++f) s += xin[e][f] * w1[f * 32 + c];
        h1[e][c] = fmaxf(s, 0.f);
    }
    __syncthreads();
    {
        int e = tid / 32, c = tid % 32;
        int n = n0 + e;
        if (n < N_NODES) {
            float s = b2[c];
#pragma unroll
            for (int f = 0; f < 32; ++f) s += h1[e][f] * w2[f * 32 + c];
            na[n * 112 + c] = s;
        }
    }
}

// ---------------------------------------------------------------------------
// K2: per-edge precompute
// ---------------------------------------------------------------------------
__global__ void kedgepre(const float* __restrict__ pos, const float* __restrict__ eattr_in,
                         const float* __restrict__ semb, const int* __restrict__ ei,
                         const float* __restrict__ w1, const float* __restrict__ b1,
                         const float* __restrict__ w2, const float* __restrict__ b2,
                         float* __restrict__ sh, float* __restrict__ eemb, int* __restrict__ cnt)
{
    __shared__ float ea[8][86];
    __shared__ float h1[8][32];
    __shared__ float dl[8];
    __shared__ int   sl[8];
    int tid = threadIdx.x;
    int e0  = blockIdx.x * 8;
    if (tid < 8) {
        int ge = e0 + tid;
        int s = ei[ge], d = ei[N_EDGES + ge];
        sl[tid] = s;
        float dx = pos[d * 3 + 0] - pos[s * 3 + 0];
        float dy = pos[d * 3 + 1] - pos[s * 3 + 1];
        float dz = pos[d * 3 + 2] - pos[s * 3 + 2];
        float dist = sqrtf(dx * dx + dy * dy + dz * dz);
        dist = fmaxf(dist, 1e-6f);
        dl[tid] = dist;
        float inv = 1.7320508f / dist;
        sh[ge * 4 + 0] = 1.f;
        sh[ge * 4 + 1] = dx * inv;
        sh[ge * 4 + 2] = dy * inv;
        sh[ge * 4 + 3] = dz * inv;
        atomicAdd(&cnt[d], 1);
    }
    __syncthreads();
    for (int idx = tid; idx < 8 * 86; idx += 256) {
        int e = idx / 86, q = idx % 86;
        int ge = e0 + e;
        float v;
        if (q < 4)       v = eattr_in[ge * 4 + q];
        else if (q < 36) v = semb[sl[e] * 32 + (q - 4)];
        else {
            int qq = q - 36;
            float off = 5.f * (float)qq / 49.f;
            float dd  = dl[e] - off;
            v = expf(-48.02f * dd * dd);
        }
        ea[e][q] = v;
    }
    __syncthreads();
    {
        int e = tid / 32, c = tid % 32;
        float s = b1[c];
        for (int f = 0; f < 86; ++f) s += ea[e][f] * w1[f * 32 + c];
        h1[e][c] = fmaxf(s, 0.f);
    }
    __syncthreads();
    {
        int e = tid / 32, c = tid % 32;
        float s = b2[c];
#pragma unroll
        for (int f = 0; f < 32; ++f) s += h1[e][f] * w2[f * 32 + c];
        eemb[(e0 + e) * 32 + c] = s;
    }
}

// ---------------------------------------------------------------------------
// K3: fused fc1(f32) -> fc2(bf16 MFMA) -> TP epilogue (compile-time paths).
// 32 edges/block, 4 waves. Wave w owns col-tiles jt = path-segmented, jt%4==w.
// All path metadata (kind/coef/offsets) are immediates via unrolled path loop.
// ---------------------------------------------------------------------------
template <int L>
__global__ __launch_bounds__(256, 2) void ktp(
    const float* __restrict__ na, const float* __restrict__ eemb,
    const float* __restrict__ sh, const int* __restrict__ ei,
    const float* __restrict__ fc1w, const float* __restrict__ fc1b,
    const unsigned short* __restrict__ wpk, const float* __restrict__ fc2b,
    float* __restrict__ out_tp)
{
    using C = PC<L>;
    constexpr int DIN  = (L == 0 ? 32 : L == 1 ? 56 : L == 2 ? 80 : 112);
    constexpr int DOUT = (L == 0 ? 56 : L == 1 ? 80 : 112);

    // uni: [0..3071] eac(32x96) ; [3072..6271] hbuf(32x100) ; later oacc(32x113) @0
    alignas(16) __shared__ float uni[6272];
    alignas(16) __shared__ float xs[32 * 113];
    __shared__ float shl4[32 * 4];
    __shared__ int   sdn[32], ddn[32];

    const int tid  = threadIdx.x;
    const int lane = tid & 63;
    const int wid  = tid >> 6;
    const int e0   = blockIdx.x * 32;

    if (tid < 32) { sdn[tid] = ei[e0 + tid]; ddn[tid] = ei[N_EDGES + e0 + tid]; }
    __syncthreads();

    for (int idx = tid; idx < 32 * 96; idx += 256) {
        int e = idx / 96, c = idx % 96;
        float v;
        if (c < 32)      v = eemb[(e0 + e) * 32 + c];
        else if (c < 64) v = na[sdn[e] * 112 + (c - 32)];
        else             v = na[ddn[e] * 112 + (c - 64)];
        uni[idx] = v;
    }
    for (int idx = tid; idx < 32 * DIN; idx += 256) {
        int e = idx / DIN, d = idx % DIN;
        xs[e * 113 + d] = na[sdn[e] * 112 + d];
    }
    if (tid < 128) shl4[tid] = sh[e0 * 4 + tid];
    __syncthreads();

    // fc1: h = relu(eac @ fc1w + b) -> hbuf (row pad 100), f32x4 LDS reads
    for (int oi = tid; oi < 32 * 96; oi += 256) {
        int e = oi / 96, c = oi % 96;
        float s = fc1b[c];
#pragma unroll 4
        for (int f = 0; f < 96; f += 4) {
            f32x4 xv = *(const f32x4*)&uni[e * 96 + f];
            s += xv.x * fc1w[(f + 0) * 96 + c];
            s += xv.y * fc1w[(f + 1) * 96 + c];
            s += xv.z * fc1w[(f + 2) * 96 + c];
            s += xv.w * fc1w[(f + 3) * 96 + c];
        }
        uni[3072 + e * 100 + c] = fmaxf(s, 0.f);
    }
    __syncthreads();

    // A fragments: afrag[mt][t], lane holds h[16mt + (lane&15)][32t + 8*(lane>>4) + i]
    bf16x8 afrag[2][3];
    {
        int m = lane & 15, g = lane >> 4;
#pragma unroll
        for (int mt = 0; mt < 2; ++mt)
#pragma unroll
        for (int t = 0; t < 3; ++t) {
            const float* hp = &uni[3072 + (16 * mt + m) * 100 + 32 * t + 8 * g];
            f32x4 h0 = *(const f32x4*)hp;
            f32x4 h1 = *(const f32x4*)(hp + 4);
            bf16x8 a;
            a[0] = (short)f2bf(h0.x); a[1] = (short)f2bf(h0.y);
            a[2] = (short)f2bf(h0.z); a[3] = (short)f2bf(h0.w);
            a[4] = (short)f2bf(h1.x); a[5] = (short)f2bf(h1.y);
            a[6] = (short)f2bf(h1.z); a[7] = (short)f2bf(h1.w);
            afrag[mt][t] = a;
        }
    }
    // sh components for this lane's 8 epilogue edges
    float sy1[8], sy2[8], sy3[8];
#pragma unroll
    for (int mt = 0; mt < 2; ++mt)
#pragma unroll
    for (int r = 0; r < 4; ++r) {
        int e = mt * 16 + (lane >> 4) * 4 + r;
        sy1[mt * 4 + r] = shl4[e * 4 + 1];
        sy2[mt * 4 + r] = shl4[e * 4 + 2];
        sy3[mt * 4 + r] = shl4[e * 4 + 3];
    }
    __syncthreads();                       // all reads of hbuf done
    for (int idx = tid; idx < 32 * 113; idx += 256) uni[idx] = 0.f;   // oacc := 0
    __syncthreads();

    // fc2 via MFMA + fused TP epilogue; compile-time path constants.
    const bf16x8* wp = (const bf16x8*)wpk;
    const int ebase = (lane >> 4) * 4;
    const int lj    = lane & 15;

#pragma unroll
    for (int p = 0; p < C::NP; ++p) {
        const int jt_hi = C::woff[p + 1] / 16;
#pragma unroll 2
        for (int jt = C::woff[p] / 16 + wid; jt < jt_hi; jt += 4) {
            const int j = jt * 16 + lj;
            bf16x8 b0 = wp[(jt * 3 + 0) * 64 + lane];
            bf16x8 b1 = wp[(jt * 3 + 1) * 64 + lane];
            bf16x8 b2 = wp[(jt * 3 + 2) * 64 + lane];
            float bias = fc2b[j];
            f32x4 acc0 = {bias, bias, bias, bias};
            f32x4 acc1 = acc0;
            acc0 = __builtin_amdgcn_mfma_f32_16x16x32_bf16(afrag[0][0], b0, acc0, 0, 0, 0);
            acc1 = __builtin_amdgcn_mfma_f32_16x16x32_bf16(afrag[1][0], b0, acc1, 0, 0, 0);
            acc0 = __builtin_amdgcn_mfma_f32_16x16x32_bf16(afrag[0][1], b1, acc0, 0, 0, 0);
            acc1 = __builtin_amdgcn_mfma_f32_16x16x32_bf16(afrag[1][1], b1, acc1, 0, 0, 0);
            acc0 = __builtin_amdgcn_mfma_f32_16x16x32_bf16(afrag[0][2], b2, acc0, 0, 0, 0);
            acc1 = __builtin_amdgcn_mfma_f32_16x16x32_bf16(afrag[1][2], b2, acc1, 0, 0, 0);

            const int rel = j - C::woff[p];
            const int u   = rel >> C::l2m3[p];
            const int w3i = rel & ((1 << C::l2m3[p]) - 1);
            const float cf = C::coef[p];
            const int OUT = C::outoff[p], IN = C::inoff[p];

#pragma unroll
            for (int mt = 0; mt < 2; ++mt) {
#pragma unroll
                for (int r = 0; r < 4; ++r) {
                    const int e = mt * 16 + ebase + r;
                    const float v = (mt == 0 ? acc0[r] : acc1[r]);
                    float* oa = &uni[e * 113];
                    const float* xe = &xs[e * 113];
                    const int si = mt * 4 + r;
                    if (C::kind[p] == 0) {
                        atomicAdd(&oa[OUT + w3i], cf * xe[IN + u] * v);
                    } else if (C::kind[p] == 1) {
                        float t = cf * xe[IN + u] * v;
                        atomicAdd(&oa[OUT + 3 * w3i + 0], t * sy1[si]);
                        atomicAdd(&oa[OUT + 3 * w3i + 1], t * sy2[si]);
                        atomicAdd(&oa[OUT + 3 * w3i + 2], t * sy3[si]);
                    } else if (C::kind[p] == 2) {
                        float t = cf * v;
                        atomicAdd(&oa[OUT + 3 * w3i + 0], t * xe[IN + 3 * u + 0]);
                        atomicAdd(&oa[OUT + 3 * w3i + 1], t * xe[IN + 3 * u + 1]);
                        atomicAdd(&oa[OUT + 3 * w3i + 2], t * xe[IN + 3 * u + 2]);
                    } else if (C::kind[p] == 3) {
                        float s = xe[IN + 3 * u + 0] * sy1[si]
                                + xe[IN + 3 * u + 1] * sy2[si]
                                + xe[IN + 3 * u + 2] * sy3[si];
                        atomicAdd(&oa[OUT + w3i], cf * s * v);
                    } else {
                        float x0 = xe[IN + 3 * u + 0];
                        float x1 = xe[IN + 3 * u + 1];
                        float x2 = xe[IN + 3 * u + 2];
                        float t  = cf * v;
                        atomicAdd(&oa[OUT + 3 * w3i + 0], t * (x1 * sy3[si] - x2 * sy2[si]));
                        atomicAdd(&oa[OUT + 3 * w3i + 1], t * (x2 * sy1[si] - x0 * sy3[si]));
                        atomicAdd(&oa[OUT + 3 * w3i + 2], t * (x0 * sy2[si] - x1 * sy1[si]));
                    }
                }
            }
        }
    }
    __syncthreads();

    // scatter to out_tp[dst]
    for (int idx = tid; idx < 32 * DOUT; idx += 256) {
        int e = idx / DOUT, d = idx % DOUT;
        unsafeAtomicAdd(&out_tp[ddn[e] * 112 + d], uni[e * 113 + d]);
    }
}

// ---------------------------------------------------------------------------
// K4: out = out_tp / max(cnt,1) + pad(node_attr)
// ---------------------------------------------------------------------------
__global__ void knodeout(const float* __restrict__ tp, const int* __restrict__ cnt,
                         const float* __restrict__ na, float* __restrict__ outb,
                         int din, int dout)
{
    int idx = blockIdx.x * 256 + threadIdx.x;
    if (idx >= N_NODES * dout) return;
    int n = idx / dout, d = idx % dout;
    float c = fmaxf((float)cnt[n], 1.f);
    float v = tp[n * 112 + d] / c + (d < din ? na[n * 112 + d] : 0.f);
    outb[n * 112 + d] = v;
}

// ---------------------------------------------------------------------------
// K5: per-dim sums
// ---------------------------------------------------------------------------
__global__ void kstats(const float* __restrict__ outb, float* __restrict__ sums,
                       float* __restrict__ sumsq)
{
    int d = blockIdx.x;
    int tid = threadIdx.x;
    float s = 0.f, s2 = 0.f;
    for (int n = tid; n < N_NODES; n += 256) {
        float v = outb[n * 112 + d];
        s += v; s2 += v * v;
    }
    __shared__ float r1[256], r2[256];
    r1[tid] = s; r2[tid] = s2;
    __syncthreads();
    for (int o = 128; o > 0; o >>= 1) {
        if (tid < o) { r1[tid] += r1[tid + o]; r2[tid] += r2[tid + o]; }
        __syncthreads();
    }
    if (tid == 0) { sums[d] = r1[0]; sumsq[d] = r2[0]; }
}

// ---------------------------------------------------------------------------
// K6: finalize batchnorm scale/bias per dim
// ---------------------------------------------------------------------------
__global__ void kfin(const float* __restrict__ sums, const float* __restrict__ sumsq,
                     float* __restrict__ scale, float* __restrict__ bias,
                     int dout, int vend)
{
    int d = threadIdx.x;
    if (d >= dout) return;
    const float invN = 1.f / (float)N_NODES;
    if (d < 32 || d >= vend) {
        float m   = sums[d] * invN;
        float var = sumsq[d] * invN - m * m;
        scale[d] = rsqrtf(var + 1e-5f);
        bias[d]  = m;
    } else {
        int b = 32 + ((d - 32) / 3) * 3;
        float n2 = (sumsq[b] + sumsq[b + 1] + sumsq[b + 2]) * (invN / 3.f);
        scale[d] = rsqrtf(n2 + 1e-5f);
        bias[d]  = 0.f;
    }
}

// ---------------------------------------------------------------------------
// K7: apply normalization
// ---------------------------------------------------------------------------
__global__ void kapply(const float* __restrict__ outb, const float* __restrict__ scale,
                       const float* __restrict__ bias, float* __restrict__ dst, int dout)
{
    int idx = blockIdx.x * 256 + threadIdx.x;
    if (idx >= N_NODES * dout) return;
    int n = idx / dout, d = idx % dout;
    dst[n * 112 + d] = (outb[n * 112 + d] - bias[d]) * scale[d];
}

// ---------------------------------------------------------------------------
extern "C" void kernel_launch(void* const* d_in, const int* in_sizes, int n_in,
                              void* d_out, int out_size, void* d_ws, size_t ws_size,
                              hipStream_t stream)
{
    (void)in_sizes; (void)n_in; (void)out_size; (void)ws_size;
    const float* x     = (const float*)d_in[0];
    const float* pos   = (const float*)d_in[1];
    const float* sigma = (const float*)d_in[2];
    const float* eain  = (const float*)d_in[3];
    const float* nw1 = (const float*)d_in[4];  const float* nb1 = (const float*)d_in[5];
    const float* nw2 = (const float*)d_in[6];  const float* nb2 = (const float*)d_in[7];
    const float* ew1 = (const float*)d_in[8];  const float* eb1 = (const float*)d_in[9];
    const float* ew2 = (const float*)d_in[10]; const float* eb2 = (const float*)d_in[11];
    const float* fc1w = (const float*)d_in[12];
    const float* fc1b = (const float*)d_in[13];
    const float* fc2w[4] = {(const float*)d_in[14], (const float*)d_in[16],
                            (const float*)d_in[18], (const float*)d_in[20]};
    const float* fc2b[4] = {(const float*)d_in[15], (const float*)d_in[17],
                            (const float*)d_in[19], (const float*)d_in[21]};
    const int* ei = (const int*)d_in[22];

    float* ws   = (float*)d_ws;
    float* semb = ws + 0;            // N*32
    float* na   = ws + 320000;       // N*112
    float* outb = ws + 1440000;      // N*112
    float* tp   = ws + 2560000;      // N*112
    float* sh   = ws + 3680000;      // E*4
    float* eemb = ws + 3840000;      // E*32
    int*   cnt  = (int*)(ws + 5120000); // N
    float* sums  = ws + 5130000;     // 112
    float* sumsq = ws + 5130112;     // 112
    float* scale = ws + 5130224;     // 112
    float* bias  = ws + 5130336;     // 112
    unsigned short* wpk = (unsigned short*)(ws + 5131008);  // 798720 bf16
    float* out = (float*)d_out;

    const int NCOL_[4] = {1280, 1664, 2048, 3328};
    const size_t WOFF_[4] = {0, 122880, 282624, 479232};   // 96*NCOL cumulative

    hipMemsetAsync(cnt, 0, N_NODES * sizeof(int), stream);
    for (int L = 0; L < 4; ++L)
        kpack<<<(NCOL_[L] * 12 + 255) / 256, 256, 0, stream>>>(fc2w[L], NCOL_[L], wpk + WOFF_[L]);
    ksemb<<<(N_NODES + 255) / 256, 256, 0, stream>>>(sigma, semb);
    knodemlp<<<N_NODES / 8, 256, 0, stream>>>(x, semb, nw1, nb1, nw2, nb2, na);
    kedgepre<<<N_EDGES / 8, 256, 0, stream>>>(pos, eain, semb, ei, ew1, eb1, ew2, eb2,
                                              sh, eemb, cnt);

    const int DIN_[4]  = {32, 56, 80, 112};
    const int DOUT_[4] = {56, 80, 112, 112};
    const int VEND_[4] = {56, 80, 80, 80};
    for (int L = 0; L < 4; ++L) {
        hipMemsetAsync(tp, 0, (size_t)N_NODES * 112 * sizeof(float), stream);
        switch (L) {
        case 0: ktp<0><<<N_EDGES / 32, 256, 0, stream>>>(na, eemb, sh, ei, fc1w + 0 * 9216,
                    fc1b + 0 * 96, wpk + WOFF_[0], fc2b[0], tp); break;
        case 1: ktp<1><<<N_EDGES / 32, 256, 0, stream>>>(na, eemb, sh, ei, fc1w + 1 * 9216,
                    fc1b + 1 * 96, wpk + WOFF_[1], fc2b[1], tp); break;
        case 2: ktp<2><<<N_EDGES / 32, 256, 0, stream>>>(na, eemb, sh, ei, fc1w + 2 * 9216,
                    fc1b + 2 * 96, wpk + WOFF_[2], fc2b[2], tp); break;
        default: ktp<3><<<N_EDGES / 32, 256, 0, stream>>>(na, eemb, sh, ei, fc1w + 3 * 9216,
                    fc1b + 3 * 96, wpk + WOFF_[3], fc2b[3], tp); break;
        }
        knodeout<<<(N_NODES * DOUT_[L] + 255) / 256, 256, 0, stream>>>(tp, cnt, na, outb,
                                                                       DIN_[L], DOUT_[L]);
        kstats<<<DOUT_[L], 256, 0, stream>>>(outb, sums, sumsq);
        kfin<<<1, 128, 0, stream>>>(sums, sumsq, scale, bias, DOUT_[L], VEND_[L]);
        float* dstp = (L == 3) ? out : na;
        kapply<<<(N_NODES * DOUT_[L] + 255) / 256, 256, 0, stream>>>(outb, scale, bias,
                                                                     dstp, DOUT_[L]);
    }
}

// Round 7
// 1228.589 us; speedup vs baseline: 3.0005x; 2.2993x over previous
//
#include <hip/hip_runtime.h>
#include <math.h>

#define N_NODES 10000
#define N_EDGES 40000

typedef __attribute__((ext_vector_type(8))) short bf16x8;
typedef __attribute__((ext_vector_type(4))) float f32x4;

__device__ inline unsigned short f2bf(float f) {
    unsigned u = __float_as_uint(f);
    return (unsigned short)((u + 0x7FFFu + ((u >> 16) & 1u)) >> 16);
}

__device__ inline void lds_add(float* p, float v) {
    __hip_atomic_fetch_add(p, v, __ATOMIC_RELAXED, __HIP_MEMORY_SCOPE_WORKGROUP);
}

// ---------------------------------------------------------------------------
// Compile-time tensor-product path tables.
// kind: 0=(0,0,0) 1=(0,1,1) 2=(1,0,1) 3=(1,1,0) 4=(1,1,1)
// ---------------------------------------------------------------------------
template <int L> struct PC;
template <> struct PC<0> {
    static constexpr int NP = 2;
    static constexpr int woff[3]  = {0, 1024, 1280};
    static constexpr int l2m3[2]  = {5, 3};
    static constexpr int inoff[2] = {0, 0};
    static constexpr int outoff[2]= {0, 32};
    static constexpr int kind[2]  = {0, 1};
    static constexpr float coef[2]= {0.17677670f, 0.17677670f};
};
template <> struct PC<1> {
    static constexpr int NP = 5;
    static constexpr int woff[6]  = {0, 1024, 1280, 1344, 1600, 1664};
    static constexpr int l2m3[5]  = {5, 3, 3, 5, 3};
    static constexpr int inoff[5] = {0, 0, 32, 32, 32};
    static constexpr int outoff[5]= {0, 32, 32, 0, 56};
    static constexpr int kind[5]  = {0, 1, 2, 3, 4};
    static constexpr float coef[5]= {0.15811388f, 0.15811388f, 0.15811388f, 0.09128709f, 0.25f};
};
template <> struct PC<2> {
    static constexpr int NP = 8;
    static constexpr int woff[9]  = {0, 1024, 1280, 1344, 1600, 1664, 1728, 1792, 2048};
    static constexpr int l2m3[8]  = {5, 3, 3, 5, 3, 3, 3, 5};
    static constexpr int inoff[8] = {0, 0, 32, 32, 32, 56, 56, 56};
    static constexpr int outoff[8]= {0, 32, 32, 0, 56, 56, 32, 80};
    static constexpr int kind[8]  = {0, 1, 2, 3, 4, 2, 4, 3};
    static constexpr float coef[8]= {0.15811388f, 0.14433757f, 0.14433757f, 0.09128709f,
                                     0.17677670f, 0.25f, 0.10206207f, 0.20412415f};
};
template <> struct PC<3> {
    static constexpr int NP = 10;
    static constexpr int woff[11] = {0, 1024, 1280, 1344, 1600, 1664, 1728, 1792, 2048, 3072, 3328};
    static constexpr int l2m3[10] = {5, 3, 3, 5, 3, 3, 3, 5, 5, 3};
    static constexpr int inoff[10]= {0, 0, 32, 32, 32, 56, 56, 56, 80, 80};
    static constexpr int outoff[10]={0, 32, 32, 0, 56, 56, 32, 80, 80, 56};
    static constexpr int kind[10] = {0, 1, 2, 3, 4, 2, 4, 3, 0, 1};
    static constexpr float coef[10]={0.15811388f, 0.14433757f, 0.14433757f, 0.09128709f,
                                     0.10206207f, 0.14433757f, 0.10206207f, 0.09128709f,
                                     0.15811388f, 0.14433757f};
};

// ---------------------------------------------------------------------------
// kpack: f32 weight [96][ncol] -> bf16 B-fragment-packed layout.
// ---------------------------------------------------------------------------
__global__ void kpack(const float* __restrict__ w, int ncol, unsigned short* __restrict__ dst)
{
    int idx = blockIdx.x * 256 + threadIdx.x;
    if (idx >= ncol * 12) return;
    int lane = idx & 63;
    int rest = idx >> 6;
    int t  = rest % 3;
    int jt = rest / 3;
    int n  = jt * 16 + (lane & 15);
    int k0 = 32 * t + 8 * (lane >> 4);
    bf16x8 v;
#pragma unroll
    for (int i = 0; i < 8; ++i) v[i] = (short)f2bf(w[(size_t)(k0 + i) * ncol + n]);
    *(bf16x8*)(dst + (size_t)idx * 8) = v;
}

// ---------------------------------------------------------------------------
__global__ void ksemb(const float* __restrict__ sigma, float* __restrict__ semb)
{
    int n = blockIdx.x * 256 + threadIdx.x;
    if (n >= N_NODES) return;
    float t = logf(sigma[n] * (1.0f / 0.031415926535897934f)) * 2171.4724095f;
#pragma unroll
    for (int j = 0; j < 16; ++j) {
        float f = expf(-0.61402269f * (float)j);
        float a = t * f;
        semb[n * 32 + j]      = sinf(a);
        semb[n * 32 + 16 + j] = cosf(a);
    }
}

// ---------------------------------------------------------------------------
__global__ void knodemlp(const float* __restrict__ x, const float* __restrict__ semb,
                         const float* __restrict__ w1, const float* __restrict__ b1,
                         const float* __restrict__ w2, const float* __restrict__ b2,
                         float* __restrict__ na)
{
    __shared__ float xin[8][106];
    __shared__ float h1[8][32];
    int tid = threadIdx.x;
    int n0  = blockIdx.x * 8;
    for (int idx = tid; idx < 8 * 106; idx += 256) {
        int e = idx / 106, q = idx % 106;
        int n = n0 + e;
        float v = 0.f;
        if (n < N_NODES) v = (q < 74) ? x[n * 74 + q] : semb[n * 32 + (q - 74)];
        xin[e][q] = v;
    }
    __syncthreads();
    {
        int e = tid / 32, c = tid % 32;
        float s = b1[c];
        for (int f = 0; f < 106; ++f) s += xin[e][f] * w1[f * 32 + c];
        h1[e][c] = fmaxf(s, 0.f);
    }
    __syncthreads();
    {
        int e = tid / 32, c = tid % 32;
        int n = n0 + e;
        if (n < N_NODES) {
            float s = b2[c];
#pragma unroll
            for (int f = 0; f < 32; ++f) s += h1[e][f] * w2[f * 32 + c];
            na[n * 112 + c] = s;
        }
    }
}

// ---------------------------------------------------------------------------
__global__ void kedgepre(const float* __restrict__ pos, const float* __restrict__ eattr_in,
                         const float* __restrict__ semb, const int* __restrict__ ei,
                         const float* __restrict__ w1, const float* __restrict__ b1,
                         const float* __restrict__ w2, const float* __restrict__ b2,
                         float* __restrict__ sh, float* __restrict__ eemb, int* __restrict__ cnt)
{
    __shared__ float ea[8][86];
    __shared__ float h1[8][32];
    __shared__ float dl[8];
    __shared__ int   sl[8];
    int tid = threadIdx.x;
    int e0  = blockIdx.x * 8;
    if (tid < 8) {
        int ge = e0 + tid;
        int s = ei[ge], d = ei[N_EDGES + ge];
        sl[tid] = s;
        float dx = pos[d * 3 + 0] - pos[s * 3 + 0];
        float dy = pos[d * 3 + 1] - pos[s * 3 + 1];
        float dz = pos[d * 3 + 2] - pos[s * 3 + 2];
        float dist = sqrtf(dx * dx + dy * dy + dz * dz);
        dist = fmaxf(dist, 1e-6f);
        dl[tid] = dist;
        float inv = 1.7320508f / dist;
        sh[ge * 4 + 0] = 1.f;
        sh[ge * 4 + 1] = dx * inv;
        sh[ge * 4 + 2] = dy * inv;
        sh[ge * 4 + 3] = dz * inv;
        atomicAdd(&cnt[d], 1);
    }
    __syncthreads();
    for (int idx = tid; idx < 8 * 86; idx += 256) {
        int e = idx / 86, q = idx % 86;
        int ge = e0 + e;
        float v;
        if (q < 4)       v = eattr_in[ge * 4 + q];
        else if (q < 36) v = semb[sl[e] * 32 + (q - 4)];
        else {
            int qq = q - 36;
            float off = 5.f * (float)qq / 49.f;
            float dd  = dl[e] - off;
            v = expf(-48.02f * dd * dd);
        }
        ea[e][q] = v;
    }
    __syncthreads();
    {
        int e = tid / 32, c = tid % 32;
        float s = b1[c];
        for (int f = 0; f < 86; ++f) s += ea[e][f] * w1[f * 32 + c];
        h1[e][c] = fmaxf(s, 0.f);
    }
    __syncthreads();
    {
        int e = tid / 32, c = tid % 32;
        float s = b2[c];
#pragma unroll
        for (int f = 0; f < 32; ++f) s += h1[e][f] * w2[f * 32 + c];
        eemb[(e0 + e) * 32 + c] = s;
    }
}

// ---------------------------------------------------------------------------
// K3: fc1(f32) -> fc2(bf16 MFMA) -> TP with REGISTER-ACCUMULATED epilogue.
// Per path, each lane's LDS target index w3i = (16*wid + lj) & mask is fixed
// across all its iterations -> accumulate in registers, one ds_add per path.
// ---------------------------------------------------------------------------
template <int L>
__global__ __launch_bounds__(256, 3) void ktp(
    const float* __restrict__ na, const float* __restrict__ eemb,
    const float* __restrict__ sh, const int* __restrict__ ei,
    const float* __restrict__ fc1w, const float* __restrict__ fc1b,
    const unsigned short* __restrict__ wpk, const float* __restrict__ fc2b,
    float* __restrict__ out_tp)
{
    using C = PC<L>;
    constexpr int DIN  = (L == 0 ? 32 : L == 1 ? 56 : L == 2 ? 80 : 112);
    constexpr int DOUT = (L == 0 ? 56 : L == 1 ? 80 : 112);

    alignas(16) __shared__ float uni[6272];   // eac(32x96)+hbuf(32x100), then oacc(32x113)@0
    alignas(16) __shared__ float xs[32 * 113];
    __shared__ float shl4[32 * 4];
    __shared__ int   sdn[32], ddn[32];

    const int tid  = threadIdx.x;
    const int lane = tid & 63;
    const int wid  = tid >> 6;
    const int e0   = blockIdx.x * 32;

    if (tid < 32) { sdn[tid] = ei[e0 + tid]; ddn[tid] = ei[N_EDGES + e0 + tid]; }
    __syncthreads();

    for (int idx = tid; idx < 32 * 96; idx += 256) {
        int e = idx / 96, c = idx % 96;
        float v;
        if (c < 32)      v = eemb[(e0 + e) * 32 + c];
        else if (c < 64) v = na[sdn[e] * 112 + (c - 32)];
        else             v = na[ddn[e] * 112 + (c - 64)];
        uni[idx] = v;
    }
    for (int idx = tid; idx < 32 * DIN; idx += 256) {
        int e = idx / DIN, d = idx % DIN;
        xs[e * 113 + d] = na[sdn[e] * 112 + d];
    }
    if (tid < 128) shl4[tid] = sh[e0 * 4 + tid];
    __syncthreads();

    // fc1: h = relu(eac @ fc1w + b) -> hbuf overlay uni[3072..] (row pad 100)
    for (int oi = tid; oi < 32 * 96; oi += 256) {
        int e = oi / 96, c = oi % 96;
        float s = fc1b[c];
#pragma unroll 4
        for (int f = 0; f < 96; f += 4) {
            f32x4 xv = *(const f32x4*)&uni[e * 96 + f];
            s += xv.x * fc1w[(f + 0) * 96 + c];
            s += xv.y * fc1w[(f + 1) * 96 + c];
            s += xv.z * fc1w[(f + 2) * 96 + c];
            s += xv.w * fc1w[(f + 3) * 96 + c];
        }
        uni[3072 + e * 100 + c] = fmaxf(s, 0.f);
    }
    __syncthreads();

    // A fragments
    bf16x8 afrag[2][3];
    {
        int m = lane & 15, g = lane >> 4;
#pragma unroll
        for (int mt = 0; mt < 2; ++mt)
#pragma unroll
        for (int t = 0; t < 3; ++t) {
            const float* hp = &uni[3072 + (16 * mt + m) * 100 + 32 * t + 8 * g];
            f32x4 h0 = *(const f32x4*)hp;
            f32x4 h1 = *(const f32x4*)(hp + 4);
            bf16x8 a;
            a[0] = (short)f2bf(h0.x); a[1] = (short)f2bf(h0.y);
            a[2] = (short)f2bf(h0.z); a[3] = (short)f2bf(h0.w);
            a[4] = (short)f2bf(h1.x); a[5] = (short)f2bf(h1.y);
            a[6] = (short)f2bf(h1.z); a[7] = (short)f2bf(h1.w);
            afrag[mt][t] = a;
        }
    }
    float sy1[8], sy2[8], sy3[8];
#pragma unroll
    for (int mt = 0; mt < 2; ++mt)
#pragma unroll
    for (int r = 0; r < 4; ++r) {
        int e = mt * 16 + (lane >> 4) * 4 + r;
        sy1[mt * 4 + r] = shl4[e * 4 + 1];
        sy2[mt * 4 + r] = shl4[e * 4 + 2];
        sy3[mt * 4 + r] = shl4[e * 4 + 3];
    }
    __syncthreads();
    for (int idx = tid; idx < 32 * 113; idx += 256) uni[idx] = 0.f;   // oacc := 0
    __syncthreads();

    const bf16x8* wp = (const bf16x8*)wpk;
    const int ebase = (lane >> 4) * 4;
    const int lj    = lane & 15;

#pragma unroll
    for (int p = 0; p < C::NP; ++p) {
        const int iters = (C::woff[p + 1] - C::woff[p]) / 64;   // tiles/4
        const int jt0   = C::woff[p] / 16;
        const int mask  = (1 << C::l2m3[p]) - 1;
        const int w3i   = (16 * wid + lj) & mask;
        const float cf  = C::coef[p];
        const int IN = C::inoff[p], OUT = C::outoff[p];

        float Ta[8], Tb[8], Tc[8];
#pragma unroll
        for (int s = 0; s < 8; ++s) { Ta[s] = 0.f; Tb[s] = 0.f; Tc[s] = 0.f; }

        for (int i = 0; i < iters; ++i) {
            const int jt = jt0 + 4 * i + wid;
            bf16x8 b0 = wp[(jt * 3 + 0) * 64 + lane];
            bf16x8 b1 = wp[(jt * 3 + 1) * 64 + lane];
            bf16x8 b2 = wp[(jt * 3 + 2) * 64 + lane];
            float bias = fc2b[jt * 16 + lj];
            f32x4 acc0 = {bias, bias, bias, bias};
            f32x4 acc1 = acc0;
            acc0 = __builtin_amdgcn_mfma_f32_16x16x32_bf16(afrag[0][0], b0, acc0, 0, 0, 0);
            acc1 = __builtin_amdgcn_mfma_f32_16x16x32_bf16(afrag[1][0], b0, acc1, 0, 0, 0);
            acc0 = __builtin_amdgcn_mfma_f32_16x16x32_bf16(afrag[0][1], b1, acc0, 0, 0, 0);
            acc1 = __builtin_amdgcn_mfma_f32_16x16x32_bf16(afrag[1][1], b1, acc1, 0, 0, 0);
            acc0 = __builtin_amdgcn_mfma_f32_16x16x32_bf16(afrag[0][2], b2, acc0, 0, 0, 0);
            acc1 = __builtin_amdgcn_mfma_f32_16x16x32_bf16(afrag[1][2], b2, acc1, 0, 0, 0);

            const int u = ((4 * i + wid) * 16 + lj) >> C::l2m3[p];

#pragma unroll
            for (int mt = 0; mt < 2; ++mt) {
#pragma unroll
                for (int r = 0; r < 4; ++r) {
                    const int e  = mt * 16 + ebase + r;
                    const int si = mt * 4 + r;
                    const float v = (mt == 0 ? acc0[r] : acc1[r]);
                    const float* xe = &xs[e * 113 + IN];
                    if (C::kind[p] == 0 || C::kind[p] == 1) {
                        Ta[si] += xe[u] * v;
                    } else if (C::kind[p] == 2) {
                        Ta[si] += xe[3 * u + 0] * v;
                        Tb[si] += xe[3 * u + 1] * v;
                        Tc[si] += xe[3 * u + 2] * v;
                    } else if (C::kind[p] == 3) {
                        Ta[si] += (xe[3 * u + 0] * sy1[si]
                                 + xe[3 * u + 1] * sy2[si]
                                 + xe[3 * u + 2] * sy3[si]) * v;
                    } else {
                        float x0 = xe[3 * u + 0], x1 = xe[3 * u + 1], x2 = xe[3 * u + 2];
                        Ta[si] += (x1 * sy3[si] - x2 * sy2[si]) * v;
                        Tb[si] += (x2 * sy1[si] - x0 * sy3[si]) * v;
                        Tc[si] += (x0 * sy2[si] - x1 * sy1[si]) * v;
                    }
                }
            }
        }

        // one LDS add per (slot, component) per path
#pragma unroll
        for (int mt = 0; mt < 2; ++mt) {
#pragma unroll
            for (int r = 0; r < 4; ++r) {
                const int e  = mt * 16 + ebase + r;
                const int si = mt * 4 + r;
                float* oa = &uni[e * 113 + OUT];
                if (C::kind[p] == 0 || C::kind[p] == 3) {
                    lds_add(&oa[w3i], cf * Ta[si]);
                } else if (C::kind[p] == 1) {
                    lds_add(&oa[3 * w3i + 0], cf * Ta[si] * sy1[si]);
                    lds_add(&oa[3 * w3i + 1], cf * Ta[si] * sy2[si]);
                    lds_add(&oa[3 * w3i + 2], cf * Ta[si] * sy3[si]);
                } else {
                    lds_add(&oa[3 * w3i + 0], cf * Ta[si]);
                    lds_add(&oa[3 * w3i + 1], cf * Tb[si]);
                    lds_add(&oa[3 * w3i + 2], cf * Tc[si]);
                }
            }
        }
    }
    __syncthreads();

    for (int idx = tid; idx < 32 * DOUT; idx += 256) {
        int e = idx / DOUT, d = idx % DOUT;
        unsafeAtomicAdd(&out_tp[ddn[e] * 112 + d], uni[e * 113 + d]);
    }
}

// ---------------------------------------------------------------------------
__global__ void knodeout(const float* __restrict__ tp, const int* __restrict__ cnt,
                         const float* __restrict__ na, float* __restrict__ outb,
                         int din, int dout)
{
    int idx = blockIdx.x * 256 + threadIdx.x;
    if (idx >= N_NODES * dout) return;
    int n = idx / dout, d = idx % dout;
    float c = fmaxf((float)cnt[n], 1.f);
    float v = tp[n * 112 + d] / c + (d < din ? na[n * 112 + d] : 0.f);
    outb[n * 112 + d] = v;
}

// ---------------------------------------------------------------------------
__global__ void kstats(const float* __restrict__ outb, float* __restrict__ sums,
                       float* __restrict__ sumsq)
{
    int d = blockIdx.x;
    int tid = threadIdx.x;
    float s = 0.f, s2 = 0.f;
    for (int n = tid; n < N_NODES; n += 256) {
        float v = outb[n * 112 + d];
        s += v; s2 += v * v;
    }
    __shared__ float r1[256], r2[256];
    r1[tid] = s; r2[tid] = s2;
    __syncthreads();
    for (int o = 128; o > 0; o >>= 1) {
        if (tid < o) { r1[tid] += r1[tid + o]; r2[tid] += r2[tid + o]; }
        __syncthreads();
    }
    if (tid == 0) { sums[d] = r1[0]; sumsq[d] = r2[0]; }
}

// ---------------------------------------------------------------------------
__global__ void kfin(const float* __restrict__ sums, const float* __restrict__ sumsq,
                     float* __restrict__ scale, float* __restrict__ bias,
                     int dout, int vend)
{
    int d = threadIdx.x;
    if (d >= dout) return;
    const float invN = 1.f / (float)N_NODES;
    if (d < 32 || d >= vend) {
        float m   = sums[d] * invN;
        float var = sumsq[d] * invN - m * m;
        scale[d] = rsqrtf(var + 1e-5f);
        bias[d]  = m;
    } else {
        int b = 32 + ((d - 32) / 3) * 3;
        float n2 = (sumsq[b] + sumsq[b + 1] + sumsq[b + 2]) * (invN / 3.f);
        scale[d] = rsqrtf(n2 + 1e-5f);
        bias[d]  = 0.f;
    }
}

// ---------------------------------------------------------------------------
__global__ void kapply(const float* __restrict__ outb, const float* __restrict__ scale,
                       const float* __restrict__ bias, float* __restrict__ dst, int dout)
{
    int idx = blockIdx.x * 256 + threadIdx.x;
    if (idx >= N_NODES * dout) return;
    int n = idx / dout, d = idx % dout;
    dst[n * 112 + d] = (outb[n * 112 + d] - bias[d]) * scale[d];
}

// ---------------------------------------------------------------------------
extern "C" void kernel_launch(void* const* d_in, const int* in_sizes, int n_in,
                              void* d_out, int out_size, void* d_ws, size_t ws_size,
                              hipStream_t stream)
{
    (void)in_sizes; (void)n_in; (void)out_size; (void)ws_size;
    const float* x     = (const float*)d_in[0];
    const float* pos   = (const float*)d_in[1];
    const float* sigma = (const float*)d_in[2];
    const float* eain  = (const float*)d_in[3];
    const float* nw1 = (const float*)d_in[4];  const float* nb1 = (const float*)d_in[5];
    const float* nw2 = (const float*)d_in[6];  const float* nb2 = (const float*)d_in[7];
    const float* ew1 = (const float*)d_in[8];  const float* eb1 = (const float*)d_in[9];
    const float* ew2 = (const float*)d_in[10]; const float* eb2 = (const float*)d_in[11];
    const float* fc1w = (const float*)d_in[12];
    const float* fc1b = (const float*)d_in[13];
    const float* fc2w[4] = {(const float*)d_in[14], (const float*)d_in[16],
                            (const float*)d_in[18], (const float*)d_in[20]};
    const float* fc2b[4] = {(const float*)d_in[15], (const float*)d_in[17],
                            (const float*)d_in[19], (const float*)d_in[21]};
    const int* ei = (const int*)d_in[22];

    float* ws   = (float*)d_ws;
    float* semb = ws + 0;            // N*32
    float* na   = ws + 320000;       // N*112
    float* outb = ws + 1440000;      // N*112
    float* tp   = ws + 2560000;      // N*112
    float* sh   = ws + 3680000;      // E*4
    float* eemb = ws + 3840000;      // E*32
    int*   cnt  = (int*)(ws + 5120000); // N
    float* sums  = ws + 5130000;     // 112
    float* sumsq = ws + 5130112;     // 112
    float* scale = ws + 5130224;     // 112
    float* bias  = ws + 5130336;     // 112
    unsigned short* wpk = (unsigned short*)(ws + 5131008);  // 798720 bf16
    float* out = (float*)d_out;

    const int NCOL_[4] = {1280, 1664, 2048, 3328};
    const size_t WOFF_[4] = {0, 122880, 282624, 479232};

    hipMemsetAsync(cnt, 0, N_NODES * sizeof(int), stream);
    for (int L = 0; L < 4; ++L)
        kpack<<<(NCOL_[L] * 12 + 255) / 256, 256, 0, stream>>>(fc2w[L], NCOL_[L], wpk + WOFF_[L]);
    ksemb<<<(N_NODES + 255) / 256, 256, 0, stream>>>(sigma, semb);
    knodemlp<<<N_NODES / 8, 256, 0, stream>>>(x, semb, nw1, nb1, nw2, nb2, na);
    kedgepre<<<N_EDGES / 8, 256, 0, stream>>>(pos, eain, semb, ei, ew1, eb1, ew2, eb2,
                                              sh, eemb, cnt);

    const int DIN_[4]  = {32, 56, 80, 112};
    const int DOUT_[4] = {56, 80, 112, 112};
    const int VEND_[4] = {56, 80, 80, 80};
    for (int L = 0; L < 4; ++L) {
        hipMemsetAsync(tp, 0, (size_t)N_NODES * 112 * sizeof(float), stream);
        switch (L) {
        case 0: ktp<0><<<N_EDGES / 32, 256, 0, stream>>>(na, eemb, sh, ei, fc1w + 0 * 9216,
                    fc1b + 0 * 96, wpk + WOFF_[0], fc2b[0], tp); break;
        case 1: ktp<1><<<N_EDGES / 32, 256, 0, stream>>>(na, eemb, sh, ei, fc1w + 1 * 9216,
                    fc1b + 1 * 96, wpk + WOFF_[1], fc2b[1], tp); break;
        case 2: ktp<2><<<N_EDGES / 32, 256, 0, stream>>>(na, eemb, sh, ei, fc1w + 2 * 9216,
                    fc1b + 2 * 96, wpk + WOFF_[2], fc2b[2], tp); break;
        default: ktp<3><<<N_EDGES / 32, 256, 0, stream>>>(na, eemb, sh, ei, fc1w + 3 * 9216,
                    fc1b + 3 * 96, wpk + WOFF_[3], fc2b[3], tp); break;
        }
        knodeout<<<(N_NODES * DOUT_[L] + 255) / 256, 256, 0, stream>>>(tp, cnt, na, outb,
                                                                       DIN_[L], DOUT_[L]);
        kstats<<<DOUT_[L], 256, 0, stream>>>(outb, sums, sumsq);
        kfin<<<1, 128, 0, stream>>>(sums, sumsq, scale, bias, DOUT_[L], VEND_[L]);
        float* dstp = (L == 3) ? out : na;
        kapply<<<(N_NODES * DOUT_[L] + 255) / 256, 256, 0, stream>>>(outb, scale, bias,
                                                                     dstp, DOUT_[L]);
    }
}

// Round 8
// 1178.199 us; speedup vs baseline: 3.1288x; 1.0428x over previous
//
#include <hip/hip_runtime.h>
#include <math.h>

#define N_NODES 10000
#define N_EDGES 40000

typedef __attribute__((ext_vector_type(8))) short bf16x8;
typedef __attribute__((ext_vector_type(4))) float f32x4;

__device__ inline unsigned short f2bf(float f) {
    unsigned u = __float_as_uint(f);
    return (unsigned short)((u + 0x7FFFu + ((u >> 16) & 1u)) >> 16);
}

__device__ inline void lds_add(float* p, float v) {
    __hip_atomic_fetch_add(p, v, __ATOMIC_RELAXED, __HIP_MEMORY_SCOPE_WORKGROUP);
}

__device__ inline bf16x8 pack8(const float* p) {
    f32x4 a0 = *(const f32x4*)p;
    f32x4 a1 = *(const f32x4*)(p + 4);
    bf16x8 r;
    r[0] = (short)f2bf(a0.x); r[1] = (short)f2bf(a0.y);
    r[2] = (short)f2bf(a0.z); r[3] = (short)f2bf(a0.w);
    r[4] = (short)f2bf(a1.x); r[5] = (short)f2bf(a1.y);
    r[6] = (short)f2bf(a1.z); r[7] = (short)f2bf(a1.w);
    return r;
}

// ---------------------------------------------------------------------------
// Compile-time tensor-product path tables.
// kind: 0=(0,0,0) 1=(0,1,1) 2=(1,0,1) 3=(1,1,0) 4=(1,1,1)
// ---------------------------------------------------------------------------
template <int L> struct PC;
template <> struct PC<0> {
    static constexpr int NP = 2;
    static constexpr int woff[3]  = {0, 1024, 1280};
    static constexpr int l2m3[2]  = {5, 3};
    static constexpr int inoff[2] = {0, 0};
    static constexpr int outoff[2]= {0, 32};
    static constexpr int kind[2]  = {0, 1};
    static constexpr float coef[2]= {0.17677670f, 0.17677670f};
};
template <> struct PC<1> {
    static constexpr int NP = 5;
    static constexpr int woff[6]  = {0, 1024, 1280, 1344, 1600, 1664};
    static constexpr int l2m3[5]  = {5, 3, 3, 5, 3};
    static constexpr int inoff[5] = {0, 0, 32, 32, 32};
    static constexpr int outoff[5]= {0, 32, 32, 0, 56};
    static constexpr int kind[5]  = {0, 1, 2, 3, 4};
    static constexpr float coef[5]= {0.15811388f, 0.15811388f, 0.15811388f, 0.09128709f, 0.25f};
};
template <> struct PC<2> {
    static constexpr int NP = 8;
    static constexpr int woff[9]  = {0, 1024, 1280, 1344, 1600, 1664, 1728, 1792, 2048};
    static constexpr int l2m3[8]  = {5, 3, 3, 5, 3, 3, 3, 5};
    static constexpr int inoff[8] = {0, 0, 32, 32, 32, 56, 56, 56};
    static constexpr int outoff[8]= {0, 32, 32, 0, 56, 56, 32, 80};
    static constexpr int kind[8]  = {0, 1, 2, 3, 4, 2, 4, 3};
    static constexpr float coef[8]= {0.15811388f, 0.14433757f, 0.14433757f, 0.09128709f,
                                     0.17677670f, 0.25f, 0.10206207f, 0.20412415f};
};
template <> struct PC<3> {
    static constexpr int NP = 10;
    static constexpr int woff[11] = {0, 1024, 1280, 1344, 1600, 1664, 1728, 1792, 2048, 3072, 3328};
    static constexpr int l2m3[10] = {5, 3, 3, 5, 3, 3, 3, 5, 5, 3};
    static constexpr int inoff[10]= {0, 0, 32, 32, 32, 56, 56, 56, 80, 80};
    static constexpr int outoff[10]={0, 32, 32, 0, 56, 56, 32, 80, 80, 56};
    static constexpr int kind[10] = {0, 1, 2, 3, 4, 2, 4, 3, 0, 1};
    static constexpr float coef[10]={0.15811388f, 0.14433757f, 0.14433757f, 0.09128709f,
                                     0.10206207f, 0.14433757f, 0.10206207f, 0.09128709f,
                                     0.15811388f, 0.14433757f};
};

// ---------------------------------------------------------------------------
// kpack: f32 weight [96][ncol] -> bf16 B-fragment-packed layout.
// frag idx = (jt*3+t)*64+lane ; elem i = w[32t+8*(lane>>4)+i][jt*16+(lane&15)]
// ---------------------------------------------------------------------------
__global__ void kpack(const float* __restrict__ w, int ncol, unsigned short* __restrict__ dst)
{
    int idx = blockIdx.x * 256 + threadIdx.x;
    if (idx >= ncol * 12) return;
    int lane = idx & 63;
    int rest = idx >> 6;
    int t  = rest % 3;
    int jt = rest / 3;
    int n  = jt * 16 + (lane & 15);
    int k0 = 32 * t + 8 * (lane >> 4);
    bf16x8 v;
#pragma unroll
    for (int i = 0; i < 8; ++i) v[i] = (short)f2bf(w[(size_t)(k0 + i) * ncol + n]);
    *(bf16x8*)(dst + (size_t)idx * 8) = v;
}

// ---------------------------------------------------------------------------
__global__ void ksemb(const float* __restrict__ sigma, float* __restrict__ semb)
{
    int n = blockIdx.x * 256 + threadIdx.x;
    if (n >= N_NODES) return;
    float t = logf(sigma[n] * (1.0f / 0.031415926535897934f)) * 2171.4724095f;
#pragma unroll
    for (int j = 0; j < 16; ++j) {
        float f = expf(-0.61402269f * (float)j);
        float a = t * f;
        semb[n * 32 + j]      = sinf(a);
        semb[n * 32 + 16 + j] = cosf(a);
    }
}

// ---------------------------------------------------------------------------
__global__ void knodemlp(const float* __restrict__ x, const float* __restrict__ semb,
                         const float* __restrict__ w1, const float* __restrict__ b1,
                         const float* __restrict__ w2, const float* __restrict__ b2,
                         float* __restrict__ na)
{
    __shared__ float xin[8][106];
    __shared__ float h1[8][32];
    int tid = threadIdx.x;
    int n0  = blockIdx.x * 8;
    for (int idx = tid; idx < 8 * 106; idx += 256) {
        int e = idx / 106, q = idx % 106;
        int n = n0 + e;
        float v = 0.f;
        if (n < N_NODES) v = (q < 74) ? x[n * 74 + q] : semb[n * 32 + (q - 74)];
        xin[e][q] = v;
    }
    __syncthreads();
    {
        int e = tid / 32, c = tid % 32;
        float s = b1[c];
        for (int f = 0; f < 106; ++f) s += xin[e][f] * w1[f * 32 + c];
        h1[e][c] = fmaxf(s, 0.f);
    }
    __syncthreads();
    {
        int e = tid / 32, c = tid % 32;
        int n = n0 + e;
        if (n < N_NODES) {
            float s = b2[c];
#pragma unroll
            for (int f = 0; f < 32; ++f) s += h1[e][f] * w2[f * 32 + c];
            na[n * 112 + c] = s;
        }
    }
}

// ---------------------------------------------------------------------------
__global__ void kedgepre(const float* __restrict__ pos, const float* __restrict__ eattr_in,
                         const float* __restrict__ semb, const int* __restrict__ ei,
                         const float* __restrict__ w1, const float* __restrict__ b1,
                         const float* __restrict__ w2, const float* __restrict__ b2,
                         float* __restrict__ sh, float* __restrict__ eemb, int* __restrict__ cnt)
{
    __shared__ float ea[8][86];
    __shared__ float h1[8][32];
    __shared__ float dl[8];
    __shared__ int   sl[8];
    int tid = threadIdx.x;
    int e0  = blockIdx.x * 8;
    if (tid < 8) {
        int ge = e0 + tid;
        int s = ei[ge], d = ei[N_EDGES + ge];
        sl[tid] = s;
        float dx = pos[d * 3 + 0] - pos[s * 3 + 0];
        float dy = pos[d * 3 + 1] - pos[s * 3 + 1];
        float dz = pos[d * 3 + 2] - pos[s * 3 + 2];
        float dist = sqrtf(dx * dx + dy * dy + dz * dz);
        dist = fmaxf(dist, 1e-6f);
        dl[tid] = dist;
        float inv = 1.7320508f / dist;
        sh[ge * 4 + 0] = 1.f;
        sh[ge * 4 + 1] = dx * inv;
        sh[ge * 4 + 2] = dy * inv;
        sh[ge * 4 + 3] = dz * inv;
        atomicAdd(&cnt[d], 1);
    }
    __syncthreads();
    for (int idx = tid; idx < 8 * 86; idx += 256) {
        int e = idx / 86, q = idx % 86;
        int ge = e0 + e;
        float v;
        if (q < 4)       v = eattr_in[ge * 4 + q];
        else if (q < 36) v = semb[sl[e] * 32 + (q - 4)];
        else {
            int qq = q - 36;
            float off = 5.f * (float)qq / 49.f;
            float dd  = dl[e] - off;
            v = expf(-48.02f * dd * dd);
        }
        ea[e][q] = v;
    }
    __syncthreads();
    {
        int e = tid / 32, c = tid % 32;
        float s = b1[c];
        for (int f = 0; f < 86; ++f) s += ea[e][f] * w1[f * 32 + c];
        h1[e][c] = fmaxf(s, 0.f);
    }
    __syncthreads();
    {
        int e = tid / 32, c = tid % 32;
        float s = b2[c];
#pragma unroll
        for (int f = 0; f < 32; ++f) s += h1[e][f] * w2[f * 32 + c];
        eemb[(e0 + e) * 32 + c] = s;
    }
}

// ---------------------------------------------------------------------------
// K3: fc1(bf16 MFMA, A-frags direct from global) -> fc2(bf16 MFMA, prefetched)
//     -> TP register-accumulated epilogue -> scatter.
// 32 edges/block, 4 waves. LDS ~29.7KB -> 4 blocks/CU with VGPR<=128.
// ---------------------------------------------------------------------------
template <int L>
__global__ __launch_bounds__(256, 4) void ktp(
    const float* __restrict__ na, const float* __restrict__ eemb,
    const float* __restrict__ sh, const int* __restrict__ ei,
    const unsigned short* __restrict__ w1pk, const float* __restrict__ fc1b,
    const unsigned short* __restrict__ wpk, const float* __restrict__ fc2b,
    float* __restrict__ out_tp)
{
    using C = PC<L>;
    constexpr int DIN  = (L == 0 ? 32 : L == 1 ? 56 : L == 2 ? 80 : 112);
    constexpr int DOUT = (L == 0 ? 56 : L == 1 ? 80 : 112);

    alignas(16) __shared__ float uni[3616];     // hbuf (32x100) then oacc (32x113)
    alignas(16) __shared__ float xs[3616];      // 32 x 113
    __shared__ float shl4[128];
    __shared__ int   sdn[32], ddn[32];

    const int tid  = threadIdx.x;
    const int lane = tid & 63;
    const int wid  = tid >> 6;
    const int e0   = blockIdx.x * 32;
    const int m    = lane & 15;
    const int g    = lane >> 4;

    if (tid < 32) { sdn[tid] = ei[e0 + tid]; ddn[tid] = ei[N_EDGES + e0 + tid]; }
    __syncthreads();

    // stage xs (src-node features) and sh
    for (int idx = tid; idx < 32 * DIN; idx += 256) {
        int e = idx / DIN, d = idx % DIN;
        xs[e * 113 + d] = na[sdn[e] * 112 + d];
    }
    if (tid < 128) shl4[tid] = sh[e0 * 4 + tid];

    // eac A-fragments directly from global: k-block 8g of {eemb | na[src] | na[dst]}
    bf16x8 eaf[2][3];
#pragma unroll
    for (int mt = 0; mt < 2; ++mt) {
        int e = 16 * mt + m;
        eaf[mt][0] = pack8(&eemb[(size_t)(e0 + e) * 32 + 8 * g]);
        eaf[mt][1] = pack8(&na[(size_t)sdn[e] * 112 + 8 * g]);
        eaf[mt][2] = pack8(&na[(size_t)ddn[e] * 112 + 8 * g]);
    }

    // fc1 via MFMA: wave w computes col-tiles jt = w and w+4 (if <6)
    const bf16x8* w1p = (const bf16x8*)w1pk;
#pragma unroll
    for (int pass = 0; pass < 2; ++pass) {
        int jt = wid + 4 * pass;
        if (jt < 6) {
            bf16x8 fb0 = w1p[(jt * 3 + 0) * 64 + lane];
            bf16x8 fb1 = w1p[(jt * 3 + 1) * 64 + lane];
            bf16x8 fb2 = w1p[(jt * 3 + 2) * 64 + lane];
            float bias = fc1b[jt * 16 + m];
            f32x4 a0 = {bias, bias, bias, bias};
            f32x4 a1 = a0;
            a0 = __builtin_amdgcn_mfma_f32_16x16x32_bf16(eaf[0][0], fb0, a0, 0, 0, 0);
            a1 = __builtin_amdgcn_mfma_f32_16x16x32_bf16(eaf[1][0], fb0, a1, 0, 0, 0);
            a0 = __builtin_amdgcn_mfma_f32_16x16x32_bf16(eaf[0][1], fb1, a0, 0, 0, 0);
            a1 = __builtin_amdgcn_mfma_f32_16x16x32_bf16(eaf[1][1], fb1, a1, 0, 0, 0);
            a0 = __builtin_amdgcn_mfma_f32_16x16x32_bf16(eaf[0][2], fb2, a0, 0, 0, 0);
            a1 = __builtin_amdgcn_mfma_f32_16x16x32_bf16(eaf[1][2], fb2, a1, 0, 0, 0);
#pragma unroll
            for (int r = 0; r < 4; ++r) {
                uni[(0  + 4 * g + r) * 100 + jt * 16 + m] = fmaxf(a0[r], 0.f);
                uni[(16 + 4 * g + r) * 100 + jt * 16 + m] = fmaxf(a1[r], 0.f);
            }
        }
    }
    __syncthreads();

    // A fragments of h from hbuf
    bf16x8 afrag[2][3];
#pragma unroll
    for (int mt = 0; mt < 2; ++mt)
#pragma unroll
    for (int t = 0; t < 3; ++t)
        afrag[mt][t] = pack8(&uni[(16 * mt + m) * 100 + 32 * t + 8 * g]);

    float sy1[8], sy2[8], sy3[8];
#pragma unroll
    for (int mt = 0; mt < 2; ++mt)
#pragma unroll
    for (int r = 0; r < 4; ++r) {
        int e = mt * 16 + 4 * g + r;
        sy1[mt * 4 + r] = shl4[e * 4 + 1];
        sy2[mt * 4 + r] = shl4[e * 4 + 2];
        sy3[mt * 4 + r] = shl4[e * 4 + 3];
    }
    __syncthreads();
    for (int idx = tid; idx < 3616; idx += 256) uni[idx] = 0.f;   // oacc := 0
    __syncthreads();

    const bf16x8* wp = (const bf16x8*)wpk;
    const int ebase = 4 * g;
    const int lj    = m;

#pragma unroll
    for (int p = 0; p < C::NP; ++p) {
        const int iters = (C::woff[p + 1] - C::woff[p]) / 64;
        const int jt0   = C::woff[p] / 16;
        const int mask  = (1 << C::l2m3[p]) - 1;
        const int w3i   = (16 * wid + lj) & mask;
        const float cf  = C::coef[p];
        const int IN = C::inoff[p], OUT = C::outoff[p];

        float Ta[8], Tb[8], Tc[8];
#pragma unroll
        for (int s = 0; s < 8; ++s) { Ta[s] = 0.f; Tb[s] = 0.f; Tc[s] = 0.f; }

        // prefetch first tile of this path
        int jt = jt0 + wid;
        bf16x8 nb0 = wp[(jt * 3 + 0) * 64 + lane];
        bf16x8 nb1 = wp[(jt * 3 + 1) * 64 + lane];
        bf16x8 nb2 = wp[(jt * 3 + 2) * 64 + lane];
        float nbias = fc2b[jt * 16 + lj];

        for (int i = 0; i < iters; ++i) {
            bf16x8 b0 = nb0, b1 = nb1, b2 = nb2;
            float bias = nbias;
            if (i + 1 < iters) {
                int jtn = jt0 + 4 * (i + 1) + wid;
                nb0 = wp[(jtn * 3 + 0) * 64 + lane];
                nb1 = wp[(jtn * 3 + 1) * 64 + lane];
                nb2 = wp[(jtn * 3 + 2) * 64 + lane];
                nbias = fc2b[jtn * 16 + lj];
            }
            f32x4 acc0 = {bias, bias, bias, bias};
            f32x4 acc1 = acc0;
            acc0 = __builtin_amdgcn_mfma_f32_16x16x32_bf16(afrag[0][0], b0, acc0, 0, 0, 0);
            acc1 = __builtin_amdgcn_mfma_f32_16x16x32_bf16(afrag[1][0], b0, acc1, 0, 0, 0);
            acc0 = __builtin_amdgcn_mfma_f32_16x16x32_bf16(afrag[0][1], b1, acc0, 0, 0, 0);
            acc1 = __builtin_amdgcn_mfma_f32_16x16x32_bf16(afrag[1][1], b1, acc1, 0, 0, 0);
            acc0 = __builtin_amdgcn_mfma_f32_16x16x32_bf16(afrag[0][2], b2, acc0, 0, 0, 0);
            acc1 = __builtin_amdgcn_mfma_f32_16x16x32_bf16(afrag[1][2], b2, acc1, 0, 0, 0);

            const int u = ((4 * i + wid) * 16 + lj) >> C::l2m3[p];

#pragma unroll
            for (int mt = 0; mt < 2; ++mt) {
#pragma unroll
                for (int r = 0; r < 4; ++r) {
                    const int e  = mt * 16 + ebase + r;
                    const int si = mt * 4 + r;
                    const float v = (mt == 0 ? acc0[r] : acc1[r]);
                    const float* xe = &xs[e * 113 + IN];
                    if (C::kind[p] == 0 || C::kind[p] == 1) {
                        Ta[si] += xe[u] * v;
                    } else if (C::kind[p] == 2) {
                        Ta[si] += xe[3 * u + 0] * v;
                        Tb[si] += xe[3 * u + 1] * v;
                        Tc[si] += xe[3 * u + 2] * v;
                    } else if (C::kind[p] == 3) {
                        Ta[si] += (xe[3 * u + 0] * sy1[si]
                                 + xe[3 * u + 1] * sy2[si]
                                 + xe[3 * u + 2] * sy3[si]) * v;
                    } else {
                        float x0 = xe[3 * u + 0], x1 = xe[3 * u + 1], x2 = xe[3 * u + 2];
                        Ta[si] += (x1 * sy3[si] - x2 * sy2[si]) * v;
                        Tb[si] += (x2 * sy1[si] - x0 * sy3[si]) * v;
                        Tc[si] += (x0 * sy2[si] - x1 * sy1[si]) * v;
                    }
                }
            }
        }

        // one LDS add per (slot, component) per path
#pragma unroll
        for (int mt = 0; mt < 2; ++mt) {
#pragma unroll
            for (int r = 0; r < 4; ++r) {
                const int e  = mt * 16 + ebase + r;
                const int si = mt * 4 + r;
                float* oa = &uni[e * 113 + OUT];
                if (C::kind[p] == 0 || C::kind[p] == 3) {
                    lds_add(&oa[w3i], cf * Ta[si]);
                } else if (C::kind[p] == 1) {
                    lds_add(&oa[3 * w3i + 0], cf * Ta[si] * sy1[si]);
                    lds_add(&oa[3 * w3i + 1], cf * Ta[si] * sy2[si]);
                    lds_add(&oa[3 * w3i + 2], cf * Ta[si] * sy3[si]);
                } else {
                    lds_add(&oa[3 * w3i + 0], cf * Ta[si]);
                    lds_add(&oa[3 * w3i + 1], cf * Tb[si]);
                    lds_add(&oa[3 * w3i + 2], cf * Tc[si]);
                }
            }
        }
    }
    __syncthreads();

    for (int idx = tid; idx < 32 * DOUT; idx += 256) {
        int e = idx / DOUT, d = idx % DOUT;
        unsafeAtomicAdd(&out_tp[ddn[e] * 112 + d], uni[e * 113 + d]);
    }
}

// ---------------------------------------------------------------------------
// knodestats: outb = tp/cnt + pad(na); per-dim sum/sumsq via register
// partials + one global atomic pair per thread. Coalesced row-major reads.
// grid <<<40, 512>>> : thread t<448 owns dim d=t%112, row phase q=t/112.
// ---------------------------------------------------------------------------
__global__ void knodestats(const float* __restrict__ tp, const int* __restrict__ cnt,
                           const float* __restrict__ na, float* __restrict__ outb,
                           float* __restrict__ sums, float* __restrict__ sumsq,
                           int din, int dout)
{
    int t = threadIdx.x;
    if (t >= 448) return;
    int d = t % 112;
    int q = t / 112;
    if (d >= dout) return;
    float s = 0.f, s2 = 0.f;
    for (int n = blockIdx.x * 4 + q; n < N_NODES; n += 160) {
        float c = fmaxf((float)cnt[n], 1.f);
        float v = tp[n * 112 + d] / c + (d < din ? na[n * 112 + d] : 0.f);
        outb[n * 112 + d] = v;
        s += v; s2 += v * v;
    }
    atomicAdd(&sums[d], s);
    atomicAdd(&sumsq[d], s2);
}

// ---------------------------------------------------------------------------
__global__ void kfin(const float* __restrict__ sums, const float* __restrict__ sumsq,
                     float* __restrict__ scale, float* __restrict__ bias,
                     int dout, int vend)
{
    int d = threadIdx.x;
    if (d >= dout) return;
    const float invN = 1.f / (float)N_NODES;
    if (d < 32 || d >= vend) {
        float m   = sums[d] * invN;
        float var = sumsq[d] * invN - m * m;
        scale[d] = rsqrtf(var + 1e-5f);
        bias[d]  = m;
    } else {
        int b = 32 + ((d - 32) / 3) * 3;
        float n2 = (sumsq[b] + sumsq[b + 1] + sumsq[b + 2]) * (invN / 3.f);
        scale[d] = rsqrtf(n2 + 1e-5f);
        bias[d]  = 0.f;
    }
}

// ---------------------------------------------------------------------------
__global__ void kapply(const float* __restrict__ outb, const float* __restrict__ scale,
                       const float* __restrict__ bias, float* __restrict__ dst, int dout)
{
    int idx = blockIdx.x * 256 + threadIdx.x;
    if (idx >= N_NODES * dout) return;
    int n = idx / dout, d = idx % dout;
    dst[n * 112 + d] = (outb[n * 112 + d] - bias[d]) * scale[d];
}

// ---------------------------------------------------------------------------
extern "C" void kernel_launch(void* const* d_in, const int* in_sizes, int n_in,
                              void* d_out, int out_size, void* d_ws, size_t ws_size,
                              hipStream_t stream)
{
    (void)in_sizes; (void)n_in; (void)out_size; (void)ws_size;
    const float* x     = (const float*)d_in[0];
    const float* pos   = (const float*)d_in[1];
    const float* sigma = (const float*)d_in[2];
    const float* eain  = (const float*)d_in[3];
    const float* nw1 = (const float*)d_in[4];  const float* nb1 = (const float*)d_in[5];
    const float* nw2 = (const float*)d_in[6];  const float* nb2 = (const float*)d_in[7];
    const float* ew1 = (const float*)d_in[8];  const float* eb1 = (const float*)d_in[9];
    const float* ew2 = (const float*)d_in[10]; const float* eb2 = (const float*)d_in[11];
    const float* fc1w = (const float*)d_in[12];
    const float* fc1b = (const float*)d_in[13];
    const float* fc2w[4] = {(const float*)d_in[14], (const float*)d_in[16],
                            (const float*)d_in[18], (const float*)d_in[20]};
    const float* fc2b[4] = {(const float*)d_in[15], (const float*)d_in[17],
                            (const float*)d_in[19], (const float*)d_in[21]};
    const int* ei = (const int*)d_in[22];

    float* ws   = (float*)d_ws;
    float* semb = ws + 0;            // N*32
    float* na   = ws + 320000;       // N*112
    float* outb = ws + 1440000;      // N*112
    float* tp   = ws + 2560000;      // N*112
    float* sh   = ws + 3680000;      // E*4
    float* eemb = ws + 3840000;      // E*32
    int*   cnt  = (int*)(ws + 5120000); // N
    float* sums  = ws + 5130000;     // 112
    float* sumsq = ws + 5130112;     // 112  (contiguous with sums)
    float* scale = ws + 5130224;     // 112
    float* bias  = ws + 5130336;     // 112
    unsigned short* wpk  = (unsigned short*)(ws + 5131008);  // fc2 packed: 798720 bf16
    unsigned short* w1pk = wpk + 798720;                      // fc1 packed: 4*9216 bf16
    float* out = (float*)d_out;

    const int NCOL_[4] = {1280, 1664, 2048, 3328};
    const size_t WOFF_[4] = {0, 122880, 282624, 479232};

    hipMemsetAsync(cnt, 0, N_NODES * sizeof(int), stream);
    for (int L = 0; L < 4; ++L) {
        kpack<<<(NCOL_[L] * 12 + 255) / 256, 256, 0, stream>>>(fc2w[L], NCOL_[L], wpk + WOFF_[L]);
        kpack<<<(96 * 12 + 255) / 256, 256, 0, stream>>>(fc1w + L * 9216, 96, w1pk + L * 9216);
    }
    ksemb<<<(N_NODES + 255) / 256, 256, 0, stream>>>(sigma, semb);
    knodemlp<<<N_NODES / 8, 256, 0, stream>>>(x, semb, nw1, nb1, nw2, nb2, na);
    kedgepre<<<N_EDGES / 8, 256, 0, stream>>>(pos, eain, semb, ei, ew1, eb1, ew2, eb2,
                                              sh, eemb, cnt);

    const int DIN_[4]  = {32, 56, 80, 112};
    const int DOUT_[4] = {56, 80, 112, 112};
    const int VEND_[4] = {56, 80, 80, 80};
    for (int L = 0; L < 4; ++L) {
        hipMemsetAsync(tp, 0, (size_t)N_NODES * 112 * sizeof(float), stream);
        hipMemsetAsync(sums, 0, 224 * sizeof(float), stream);
        switch (L) {
        case 0: ktp<0><<<N_EDGES / 32, 256, 0, stream>>>(na, eemb, sh, ei,
                    w1pk + 0 * 9216, fc1b + 0 * 96, wpk + WOFF_[0], fc2b[0], tp); break;
        case 1: ktp<1><<<N_EDGES / 32, 256, 0, stream>>>(na, eemb, sh, ei,
                    w1pk + 1 * 9216, fc1b + 1 * 96, wpk + WOFF_[1], fc2b[1], tp); break;
        case 2: ktp<2><<<N_EDGES / 32, 256, 0, stream>>>(na, eemb, sh, ei,
                    w1pk + 2 * 9216, fc1b + 2 * 96, wpk + WOFF_[2], fc2b[2], tp); break;
        default: ktp<3><<<N_EDGES / 32, 256, 0, stream>>>(na, eemb, sh, ei,
                    w1pk + 3 * 9216, fc1b + 3 * 96, wpk + WOFF_[3], fc2b[3], tp); break;
        }
        knodestats<<<40, 512, 0, stream>>>(tp, cnt, na, outb, sums, sumsq,
                                           DIN_[L], DOUT_[L]);
        kfin<<<1, 128, 0, stream>>>(sums, sumsq, scale, bias, DOUT_[L], VEND_[L]);
        float* dstp = (L == 3) ? out : na;
        kapply<<<(N_NODES * DOUT_[L] + 255) / 256, 256, 0, stream>>>(outb, scale, bias,
                                                                     dstp, DOUT_[L]);
    }
}

// Round 9
// 1108.400 us; speedup vs baseline: 3.3259x; 1.0630x over previous
//
#include <hip/hip_runtime.h>
#include <math.h>

#define N_NODES 10000
#define N_EDGES 40000

typedef __attribute__((ext_vector_type(8))) short bf16x8;
typedef __attribute__((ext_vector_type(4))) float f32x4;

__device__ inline unsigned short f2bf(float f) {
    unsigned u = __float_as_uint(f);
    return (unsigned short)((u + 0x7FFFu + ((u >> 16) & 1u)) >> 16);
}

__device__ inline void lds_add(float* p, float v) {
    __hip_atomic_fetch_add(p, v, __ATOMIC_RELAXED, __HIP_MEMORY_SCOPE_WORKGROUP);
}

__device__ inline bf16x8 pack8(const float* p) {
    f32x4 a0 = *(const f32x4*)p;
    f32x4 a1 = *(const f32x4*)(p + 4);
    bf16x8 r;
    r[0] = (short)f2bf(a0.x); r[1] = (short)f2bf(a0.y);
    r[2] = (short)f2bf(a0.z); r[3] = (short)f2bf(a0.w);
    r[4] = (short)f2bf(a1.x); r[5] = (short)f2bf(a1.y);
    r[6] = (short)f2bf(a1.z); r[7] = (short)f2bf(a1.w);
    return r;
}

// ---------------------------------------------------------------------------
// Compile-time tensor-product path tables.
// kind: 0=(0,0,0) 1=(0,1,1) 2=(1,0,1) 3=(1,1,0) 4=(1,1,1)
// ---------------------------------------------------------------------------
template <int L> struct PC;
template <> struct PC<0> {
    static constexpr int NP = 2;
    static constexpr int woff[3]  = {0, 1024, 1280};
    static constexpr int l2m3[2]  = {5, 3};
    static constexpr int inoff[2] = {0, 0};
    static constexpr int outoff[2]= {0, 32};
    static constexpr int kind[2]  = {0, 1};
    static constexpr float coef[2]= {0.17677670f, 0.17677670f};
};
template <> struct PC<1> {
    static constexpr int NP = 5;
    static constexpr int woff[6]  = {0, 1024, 1280, 1344, 1600, 1664};
    static constexpr int l2m3[5]  = {5, 3, 3, 5, 3};
    static constexpr int inoff[5] = {0, 0, 32, 32, 32};
    static constexpr int outoff[5]= {0, 32, 32, 0, 56};
    static constexpr int kind[5]  = {0, 1, 2, 3, 4};
    static constexpr float coef[5]= {0.15811388f, 0.15811388f, 0.15811388f, 0.09128709f, 0.25f};
};
template <> struct PC<2> {
    static constexpr int NP = 8;
    static constexpr int woff[9]  = {0, 1024, 1280, 1344, 1600, 1664, 1728, 1792, 2048};
    static constexpr int l2m3[8]  = {5, 3, 3, 5, 3, 3, 3, 5};
    static constexpr int inoff[8] = {0, 0, 32, 32, 32, 56, 56, 56};
    static constexpr int outoff[8]= {0, 32, 32, 0, 56, 56, 32, 80};
    static constexpr int kind[8]  = {0, 1, 2, 3, 4, 2, 4, 3};
    static constexpr float coef[8]= {0.15811388f, 0.14433757f, 0.14433757f, 0.09128709f,
                                     0.17677670f, 0.25f, 0.10206207f, 0.20412415f};
};
template <> struct PC<3> {
    static constexpr int NP = 10;
    static constexpr int woff[11] = {0, 1024, 1280, 1344, 1600, 1664, 1728, 1792, 2048, 3072, 3328};
    static constexpr int l2m3[10] = {5, 3, 3, 5, 3, 3, 3, 5, 5, 3};
    static constexpr int inoff[10]= {0, 0, 32, 32, 32, 56, 56, 56, 80, 80};
    static constexpr int outoff[10]={0, 32, 32, 0, 56, 56, 32, 80, 80, 56};
    static constexpr int kind[10] = {0, 1, 2, 3, 4, 2, 4, 3, 0, 1};
    static constexpr float coef[10]={0.15811388f, 0.14433757f, 0.14433757f, 0.09128709f,
                                     0.10206207f, 0.14433757f, 0.10206207f, 0.09128709f,
                                     0.15811388f, 0.14433757f};
};

// ---------------------------------------------------------------------------
// kpack: f32 weight [96][ncol] -> bf16 B-fragment-packed layout.
// ---------------------------------------------------------------------------
__global__ void kpack(const float* __restrict__ w, int ncol, unsigned short* __restrict__ dst)
{
    int idx = blockIdx.x * 256 + threadIdx.x;
    if (idx >= ncol * 12) return;
    int lane = idx & 63;
    int rest = idx >> 6;
    int t  = rest % 3;
    int jt = rest / 3;
    int n  = jt * 16 + (lane & 15);
    int k0 = 32 * t + 8 * (lane >> 4);
    bf16x8 v;
#pragma unroll
    for (int i = 0; i < 8; ++i) v[i] = (short)f2bf(w[(size_t)(k0 + i) * ncol + n]);
    *(bf16x8*)(dst + (size_t)idx * 8) = v;
}

// ---------------------------------------------------------------------------
__global__ void ksemb(const float* __restrict__ sigma, float* __restrict__ semb)
{
    int n = blockIdx.x * 256 + threadIdx.x;
    if (n >= N_NODES) return;
    float t = logf(sigma[n] * (1.0f / 0.031415926535897934f)) * 2171.4724095f;
#pragma unroll
    for (int j = 0; j < 16; ++j) {
        float f = expf(-0.61402269f * (float)j);
        float a = t * f;
        semb[n * 32 + j]      = sinf(a);
        semb[n * 32 + 16 + j] = cosf(a);
    }
}

// ---------------------------------------------------------------------------
__global__ void knodemlp(const float* __restrict__ x, const float* __restrict__ semb,
                         const float* __restrict__ w1, const float* __restrict__ b1,
                         const float* __restrict__ w2, const float* __restrict__ b2,
                         float* __restrict__ na)
{
    __shared__ float xin[8][106];
    __shared__ float h1[8][32];
    int tid = threadIdx.x;
    int n0  = blockIdx.x * 8;
    for (int idx = tid; idx < 8 * 106; idx += 256) {
        int e = idx / 106, q = idx % 106;
        int n = n0 + e;
        float v = 0.f;
        if (n < N_NODES) v = (q < 74) ? x[n * 74 + q] : semb[n * 32 + (q - 74)];
        xin[e][q] = v;
    }
    __syncthreads();
    {
        int e = tid / 32, c = tid % 32;
        float s = b1[c];
        for (int f = 0; f < 106; ++f) s += xin[e][f] * w1[f * 32 + c];
        h1[e][c] = fmaxf(s, 0.f);
    }
    __syncthreads();
    {
        int e = tid / 32, c = tid % 32;
        int n = n0 + e;
        if (n < N_NODES) {
            float s = b2[c];
#pragma unroll
            for (int f = 0; f < 32; ++f) s += h1[e][f] * w2[f * 32 + c];
            na[n * 112 + c] = s;
        }
    }
}

// ---------------------------------------------------------------------------
__global__ void kedgepre(const float* __restrict__ pos, const float* __restrict__ eattr_in,
                         const float* __restrict__ semb, const int* __restrict__ ei,
                         const float* __restrict__ w1, const float* __restrict__ b1,
                         const float* __restrict__ w2, const float* __restrict__ b2,
                         float* __restrict__ sh, float* __restrict__ eemb, int* __restrict__ cnt)
{
    __shared__ float ea[8][86];
    __shared__ float h1[8][32];
    __shared__ float dl[8];
    __shared__ int   sl[8];
    int tid = threadIdx.x;
    int e0  = blockIdx.x * 8;
    if (tid < 8) {
        int ge = e0 + tid;
        int s = ei[ge], d = ei[N_EDGES + ge];
        sl[tid] = s;
        float dx = pos[d * 3 + 0] - pos[s * 3 + 0];
        float dy = pos[d * 3 + 1] - pos[s * 3 + 1];
        float dz = pos[d * 3 + 2] - pos[s * 3 + 2];
        float dist = sqrtf(dx * dx + dy * dy + dz * dz);
        dist = fmaxf(dist, 1e-6f);
        dl[tid] = dist;
        float inv = 1.7320508f / dist;
        sh[ge * 4 + 0] = 1.f;
        sh[ge * 4 + 1] = dx * inv;
        sh[ge * 4 + 2] = dy * inv;
        sh[ge * 4 + 3] = dz * inv;
        atomicAdd(&cnt[d], 1);
    }
    __syncthreads();
    for (int idx = tid; idx < 8 * 86; idx += 256) {
        int e = idx / 86, q = idx % 86;
        int ge = e0 + e;
        float v;
        if (q < 4)       v = eattr_in[ge * 4 + q];
        else if (q < 36) v = semb[sl[e] * 32 + (q - 4)];
        else {
            int qq = q - 36;
            float off = 5.f * (float)qq / 49.f;
            float dd  = dl[e] - off;
            v = expf(-48.02f * dd * dd);
        }
        ea[e][q] = v;
    }
    __syncthreads();
    {
        int e = tid / 32, c = tid % 32;
        float s = b1[c];
        for (int f = 0; f < 86; ++f) s += ea[e][f] * w1[f * 32 + c];
        h1[e][c] = fmaxf(s, 0.f);
    }
    __syncthreads();
    {
        int e = tid / 32, c = tid % 32;
        float s = b2[c];
#pragma unroll
        for (int f = 0; f < 32; ++f) s += h1[e][f] * w2[f * 32 + c];
        eemb[(e0 + e) * 32 + c] = s;
    }
}

// ---------------------------------------------------------------------------
// K3: fc1(bf16 MFMA) -> fc2(bf16 MFMA) -> TP register-accumulated epilogue.
// 32 edges/block, 4 waves. launch_bounds(256,2): VGPR cap 256 -> NO SPILL;
// actual occupancy set by real VGPR use (~4 blocks/CU), LDS 29.7KB allows 5.
// ---------------------------------------------------------------------------
template <int L>
__global__ __launch_bounds__(256, 2) void ktp(
    const float* __restrict__ na, const float* __restrict__ eemb,
    const float* __restrict__ sh, const int* __restrict__ ei,
    const unsigned short* __restrict__ w1pk, const float* __restrict__ fc1b,
    const unsigned short* __restrict__ wpk, const float* __restrict__ fc2b,
    float* __restrict__ out_tp)
{
    using C = PC<L>;
    constexpr int DIN  = (L == 0 ? 32 : L == 1 ? 56 : L == 2 ? 80 : 112);
    constexpr int DOUT = (L == 0 ? 56 : L == 1 ? 80 : 112);

    alignas(16) __shared__ float uni[3616];     // hbuf (32x100) then oacc (32x113)
    alignas(16) __shared__ float xs[3616];      // 32 x 113
    __shared__ float shl4[128];
    __shared__ int   sdn[32], ddn[32];

    const int tid  = threadIdx.x;
    const int lane = tid & 63;
    const int wid  = tid >> 6;
    const int e0   = blockIdx.x * 32;
    const int m    = lane & 15;
    const int g    = lane >> 4;

    if (tid < 32) { sdn[tid] = ei[e0 + tid]; ddn[tid] = ei[N_EDGES + e0 + tid]; }
    __syncthreads();

    // stage xs (src-node features) and sh
    for (int idx = tid; idx < 32 * DIN; idx += 256) {
        int e = idx / DIN, d = idx % DIN;
        xs[e * 113 + d] = na[sdn[e] * 112 + d];
    }
    if (tid < 128) shl4[tid] = sh[e0 * 4 + tid];

    // eac A-fragments directly from global: k-block 8g of {eemb | na[src] | na[dst]}
    bf16x8 eaf[2][3];
#pragma unroll
    for (int mt = 0; mt < 2; ++mt) {
        int e = 16 * mt + m;
        eaf[mt][0] = pack8(&eemb[(size_t)(e0 + e) * 32 + 8 * g]);
        eaf[mt][1] = pack8(&na[(size_t)sdn[e] * 112 + 8 * g]);
        eaf[mt][2] = pack8(&na[(size_t)ddn[e] * 112 + 8 * g]);
    }

    // fc1 via MFMA: wave w computes col-tiles jt = w and w+4 (if <6)
    const bf16x8* w1p = (const bf16x8*)w1pk;
#pragma unroll
    for (int pass = 0; pass < 2; ++pass) {
        int jt = wid + 4 * pass;
        if (jt < 6) {
            bf16x8 fb0 = w1p[(jt * 3 + 0) * 64 + lane];
            bf16x8 fb1 = w1p[(jt * 3 + 1) * 64 + lane];
            bf16x8 fb2 = w1p[(jt * 3 + 2) * 64 + lane];
            float bias = fc1b[jt * 16 + m];
            f32x4 a0 = {bias, bias, bias, bias};
            f32x4 a1 = a0;
            a0 = __builtin_amdgcn_mfma_f32_16x16x32_bf16(eaf[0][0], fb0, a0, 0, 0, 0);
            a1 = __builtin_amdgcn_mfma_f32_16x16x32_bf16(eaf[1][0], fb0, a1, 0, 0, 0);
            a0 = __builtin_amdgcn_mfma_f32_16x16x32_bf16(eaf[0][1], fb1, a0, 0, 0, 0);
            a1 = __builtin_amdgcn_mfma_f32_16x16x32_bf16(eaf[1][1], fb1, a1, 0, 0, 0);
            a0 = __builtin_amdgcn_mfma_f32_16x16x32_bf16(eaf[0][2], fb2, a0, 0, 0, 0);
            a1 = __builtin_amdgcn_mfma_f32_16x16x32_bf16(eaf[1][2], fb2, a1, 0, 0, 0);
#pragma unroll
            for (int r = 0; r < 4; ++r) {
                uni[(0  + 4 * g + r) * 100 + jt * 16 + m] = fmaxf(a0[r], 0.f);
                uni[(16 + 4 * g + r) * 100 + jt * 16 + m] = fmaxf(a1[r], 0.f);
            }
        }
    }
    __syncthreads();

    // A fragments of h from hbuf
    bf16x8 afrag[2][3];
#pragma unroll
    for (int mt = 0; mt < 2; ++mt)
#pragma unroll
    for (int t = 0; t < 3; ++t)
        afrag[mt][t] = pack8(&uni[(16 * mt + m) * 100 + 32 * t + 8 * g]);

    float sy1[8], sy2[8], sy3[8];
#pragma unroll
    for (int mt = 0; mt < 2; ++mt)
#pragma unroll
    for (int r = 0; r < 4; ++r) {
        int e = mt * 16 + 4 * g + r;
        sy1[mt * 4 + r] = shl4[e * 4 + 1];
        sy2[mt * 4 + r] = shl4[e * 4 + 2];
        sy3[mt * 4 + r] = shl4[e * 4 + 3];
    }
    __syncthreads();
    for (int idx = tid; idx < 3616; idx += 256) uni[idx] = 0.f;   // oacc := 0
    __syncthreads();

    const bf16x8* wp = (const bf16x8*)wpk;
    const int ebase = 4 * g;
    const int lj    = m;

#pragma unroll
    for (int p = 0; p < C::NP; ++p) {
        const int iters = (C::woff[p + 1] - C::woff[p]) / 64;
        const int jt0   = C::woff[p] / 16;
        const int mask  = (1 << C::l2m3[p]) - 1;
        const int w3i   = (16 * wid + lj) & mask;
        const float cf  = C::coef[p];
        const int IN = C::inoff[p], OUT = C::outoff[p];

        float Ta[8], Tb[8], Tc[8];
#pragma unroll
        for (int s = 0; s < 8; ++s) { Ta[s] = 0.f; Tb[s] = 0.f; Tc[s] = 0.f; }

        for (int i = 0; i < iters; ++i) {
            const int jt = jt0 + 4 * i + wid;
            bf16x8 b0 = wp[(jt * 3 + 0) * 64 + lane];
            bf16x8 b1 = wp[(jt * 3 + 1) * 64 + lane];
            bf16x8 b2 = wp[(jt * 3 + 2) * 64 + lane];
            float bias = fc2b[jt * 16 + lj];
            f32x4 acc0 = {bias, bias, bias, bias};
            f32x4 acc1 = acc0;
            acc0 = __builtin_amdgcn_mfma_f32_16x16x32_bf16(afrag[0][0], b0, acc0, 0, 0, 0);
            acc1 = __builtin_amdgcn_mfma_f32_16x16x32_bf16(afrag[1][0], b0, acc1, 0, 0, 0);
            acc0 = __builtin_amdgcn_mfma_f32_16x16x32_bf16(afrag[0][1], b1, acc0, 0, 0, 0);
            acc1 = __builtin_amdgcn_mfma_f32_16x16x32_bf16(afrag[1][1], b1, acc1, 0, 0, 0);
            acc0 = __builtin_amdgcn_mfma_f32_16x16x32_bf16(afrag[0][2], b2, acc0, 0, 0, 0);
            acc1 = __builtin_amdgcn_mfma_f32_16x16x32_bf16(afrag[1][2], b2, acc1, 0, 0, 0);

            const int u = ((4 * i + wid) * 16 + lj) >> C::l2m3[p];

#pragma unroll
            for (int mt = 0; mt < 2; ++mt) {
#pragma unroll
                for (int r = 0; r < 4; ++r) {
                    const int e  = mt * 16 + ebase + r;
                    const int si = mt * 4 + r;
                    const float v = (mt == 0 ? acc0[r] : acc1[r]);
                    const float* xe = &xs[e * 113 + IN];
                    if (C::kind[p] == 0 || C::kind[p] == 1) {
                        Ta[si] += xe[u] * v;
                    } else if (C::kind[p] == 2) {
                        Ta[si] += xe[3 * u + 0] * v;
                        Tb[si] += xe[3 * u + 1] * v;
                        Tc[si] += xe[3 * u + 2] * v;
                    } else if (C::kind[p] == 3) {
                        Ta[si] += (xe[3 * u + 0] * sy1[si]
                                 + xe[3 * u + 1] * sy2[si]
                                 + xe[3 * u + 2] * sy3[si]) * v;
                    } else {
                        float x0 = xe[3 * u + 0], x1 = xe[3 * u + 1], x2 = xe[3 * u + 2];
                        Ta[si] += (x1 * sy3[si] - x2 * sy2[si]) * v;
                        Tb[si] += (x2 * sy1[si] - x0 * sy3[si]) * v;
                        Tc[si] += (x0 * sy2[si] - x1 * sy1[si]) * v;
                    }
                }
            }
        }

        // one LDS add per (slot, component) per path
#pragma unroll
        for (int mt = 0; mt < 2; ++mt) {
#pragma unroll
            for (int r = 0; r < 4; ++r) {
                const int e  = mt * 16 + ebase + r;
                const int si = mt * 4 + r;
                float* oa = &uni[e * 113 + OUT];
                if (C::kind[p] == 0 || C::kind[p] == 3) {
                    lds_add(&oa[w3i], cf * Ta[si]);
                } else if (C::kind[p] == 1) {
                    lds_add(&oa[3 * w3i + 0], cf * Ta[si] * sy1[si]);
                    lds_add(&oa[3 * w3i + 1], cf * Ta[si] * sy2[si]);
                    lds_add(&oa[3 * w3i + 2], cf * Ta[si] * sy3[si]);
                } else {
                    lds_add(&oa[3 * w3i + 0], cf * Ta[si]);
                    lds_add(&oa[3 * w3i + 1], cf * Tb[si]);
                    lds_add(&oa[3 * w3i + 2], cf * Tc[si]);
                }
            }
        }
    }
    __syncthreads();

    for (int idx = tid; idx < 32 * DOUT; idx += 256) {
        int e = idx / DOUT, d = idx % DOUT;
        unsafeAtomicAdd(&out_tp[ddn[e] * 112 + d], uni[e * 113 + d]);
    }
}

// ---------------------------------------------------------------------------
// knodestats: outb = tp/cnt + pad(na); per-dim sum/sumsq via register
// partials + one global atomic pair per thread.
// ---------------------------------------------------------------------------
__global__ void knodestats(const float* __restrict__ tp, const int* __restrict__ cnt,
                           const float* __restrict__ na, float* __restrict__ outb,
                           float* __restrict__ sums, float* __restrict__ sumsq,
                           int din, int dout)
{
    int t = threadIdx.x;
    if (t >= 448) return;
    int d = t % 112;
    int q = t / 112;
    if (d >= dout) return;
    float s = 0.f, s2 = 0.f;
    for (int n = blockIdx.x * 4 + q; n < N_NODES; n += 160) {
        float c = fmaxf((float)cnt[n], 1.f);
        float v = tp[n * 112 + d] / c + (d < din ? na[n * 112 + d] : 0.f);
        outb[n * 112 + d] = v;
        s += v; s2 += v * v;
    }
    atomicAdd(&sums[d], s);
    atomicAdd(&sumsq[d], s2);
}

// ---------------------------------------------------------------------------
__global__ void kfin(const float* __restrict__ sums, const float* __restrict__ sumsq,
                     float* __restrict__ scale, float* __restrict__ bias,
                     int dout, int vend)
{
    int d = threadIdx.x;
    if (d >= dout) return;
    const float invN = 1.f / (float)N_NODES;
    if (d < 32 || d >= vend) {
        float m   = sums[d] * invN;
        float var = sumsq[d] * invN - m * m;
        scale[d] = rsqrtf(var + 1e-5f);
        bias[d]  = m;
    } else {
        int b = 32 + ((d - 32) / 3) * 3;
        float n2 = (sumsq[b] + sumsq[b + 1] + sumsq[b + 2]) * (invN / 3.f);
        scale[d] = rsqrtf(n2 + 1e-5f);
        bias[d]  = 0.f;
    }
}

// ---------------------------------------------------------------------------
__global__ void kapply(const float* __restrict__ outb, const float* __restrict__ scale,
                       const float* __restrict__ bias, float* __restrict__ dst, int dout)
{
    int idx = blockIdx.x * 256 + threadIdx.x;
    if (idx >= N_NODES * dout) return;
    int n = idx / dout, d = idx % dout;
    dst[n * 112 + d] = (outb[n * 112 + d] - bias[d]) * scale[d];
}

// ---------------------------------------------------------------------------
extern "C" void kernel_launch(void* const* d_in, const int* in_sizes, int n_in,
                              void* d_out, int out_size, void* d_ws, size_t ws_size,
                              hipStream_t stream)
{
    (void)in_sizes; (void)n_in; (void)out_size; (void)ws_size;
    const float* x     = (const float*)d_in[0];
    const float* pos   = (const float*)d_in[1];
    const float* sigma = (const float*)d_in[2];
    const float* eain  = (const float*)d_in[3];
    const float* nw1 = (const float*)d_in[4];  const float* nb1 = (const float*)d_in[5];
    const float* nw2 = (const float*)d_in[6];  const float* nb2 = (const float*)d_in[7];
    const float* ew1 = (const float*)d_in[8];  const float* eb1 = (const float*)d_in[9];
    const float* ew2 = (const float*)d_in[10]; const float* eb2 = (const float*)d_in[11];
    const float* fc1w = (const float*)d_in[12];
    const float* fc1b = (const float*)d_in[13];
    const float* fc2w[4] = {(const float*)d_in[14], (const float*)d_in[16],
                            (const float*)d_in[18], (const float*)d_in[20]};
    const float* fc2b[4] = {(const float*)d_in[15], (const float*)d_in[17],
                            (const float*)d_in[19], (const float*)d_in[21]};
    const int* ei = (const int*)d_in[22];

    float* ws   = (float*)d_ws;
    float* semb = ws + 0;            // N*32
    float* na   = ws + 320000;       // N*112
    float* outb = ws + 1440000;      // N*112
    float* tp   = ws + 2560000;      // N*112
    float* sh   = ws + 3680000;      // E*4
    float* eemb = ws + 3840000;      // E*32
    int*   cnt  = (int*)(ws + 5120000); // N
    float* sums  = ws + 5130000;     // 112
    float* sumsq = ws + 5130112;     // 112
    float* scale = ws + 5130224;     // 112
    float* bias  = ws + 5130336;     // 112
    unsigned short* wpk  = (unsigned short*)(ws + 5131008);  // fc2 packed: 798720 bf16
    unsigned short* w1pk = wpk + 798720;                      // fc1 packed: 4*9216 bf16
    float* out = (float*)d_out;

    const int NCOL_[4] = {1280, 1664, 2048, 3328};
    const size_t WOFF_[4] = {0, 122880, 282624, 479232};

    hipMemsetAsync(cnt, 0, N_NODES * sizeof(int), stream);
    for (int L = 0; L < 4; ++L) {
        kpack<<<(NCOL_[L] * 12 + 255) / 256, 256, 0, stream>>>(fc2w[L], NCOL_[L], wpk + WOFF_[L]);
        kpack<<<(96 * 12 + 255) / 256, 256, 0, stream>>>(fc1w + L * 9216, 96, w1pk + L * 9216);
    }
    ksemb<<<(N_NODES + 255) / 256, 256, 0, stream>>>(sigma, semb);
    knodemlp<<<N_NODES / 8, 256, 0, stream>>>(x, semb, nw1, nb1, nw2, nb2, na);
    kedgepre<<<N_EDGES / 8, 256, 0, stream>>>(pos, eain, semb, ei, ew1, eb1, ew2, eb2,
                                              sh, eemb, cnt);

    const int DIN_[4]  = {32, 56, 80, 112};
    const int DOUT_[4] = {56, 80, 112, 112};
    const int VEND_[4] = {56, 80, 80, 80};
    for (int L = 0; L < 4; ++L) {
        hipMemsetAsync(tp, 0, (size_t)N_NODES * 112 * sizeof(float), stream);
        hipMemsetAsync(sums, 0, 224 * sizeof(float), stream);
        switch (L) {
        case 0: ktp<0><<<N_EDGES / 32, 256, 0, stream>>>(na, eemb, sh, ei,
                    w1pk + 0 * 9216, fc1b + 0 * 96, wpk + WOFF_[0], fc2b[0], tp); break;
        case 1: ktp<1><<<N_EDGES / 32, 256, 0, stream>>>(na, eemb, sh, ei,
                    w1pk + 1 * 9216, fc1b + 1 * 96, wpk + WOFF_[1], fc2b[1], tp); break;
        case 2: ktp<2><<<N_EDGES / 32, 256, 0, stream>>>(na, eemb, sh, ei,
                    w1pk + 2 * 9216, fc1b + 2 * 96, wpk + WOFF_[2], fc2b[2], tp); break;
        default: ktp<3><<<N_EDGES / 32, 256, 0, stream>>>(na, eemb, sh, ei,
                    w1pk + 3 * 9216, fc1b + 3 * 96, wpk + WOFF_[3], fc2b[3], tp); break;
        }
        knodestats<<<40, 512, 0, stream>>>(tp, cnt, na, outb, sums, sumsq,
                                           DIN_[L], DOUT_[L]);
        kfin<<<1, 128, 0, stream>>>(sums, sumsq, scale, bias, DOUT_[L], VEND_[L]);
        float* dstp = (L == 3) ? out : na;
        kapply<<<(N_NODES * DOUT_[L] + 255) / 256, 256, 0, stream>>>(outb, scale, bias,
                                                                     dstp, DOUT_[L]);
    }
}